// Round 12
// baseline (84.911 us; speedup 1.0000x reference)
//
#include <hip/hip_runtime.h>
#include <hip/hip_fp16.h>

// Fused 3-layer ReLU-RNN + linear head, MI355X (gfx950).
// T=512, B=4096, IN=4, H1=24, H2=48, H3=24, OUT=2.
//
// ROUND 12: round-11 skeleton (8-wave uniform-lag forward pipeline, S=4
// steps/interval, ring-16 LDS, counted LGKM + raw s_barrier, pre-read one
// interval ahead), retargeted at the critical wave wB (h2 recurrence,
// 6 MFMA/step):
//  (1) wid7 is now a STORE-ONLY wave (0 MFMA): the head MFMA moved into wC,
//      which owns the h3 packs in-register (head(tau-1) from previous step's
//      fd, no LDS hop; sH3 ring eliminated, sAO float2 ring added). With the
//      usual wid&3->SIMD pairing, wB (wid3) now shares SIMD3 with a 0-MFMA
//      wave: its 6 MFMAs/step get the matrix pipe exclusively.
//  (2) wB issues FB-dependent MFMAs (operand packed FIRST last step) before
//      FC-dependent ones, maximizing operand age in its dependency cycle.
// Stage lags (steps): wA(h1)=0, wD/wH(partial1)=8, wB(h2)=16,
// wE/wF(partial2)=24, wC(h3+head)=32, wS(stores)=~41. C runs one extra
// interval (i<=136) to flush head(511); its garbage recurrence tail is
// unconsumed. 140 intervals. LDS 122 KB.

#define TSEQ 512
#define NBAT 4096

typedef float    f32x4 __attribute__((ext_vector_type(4)));
typedef _Float16 f16x8 __attribute__((ext_vector_type(8)));

union BFrag { f16x8 h; unsigned u[4]; };

__device__ __forceinline__ f32x4 MF(f16x8 a, f16x8 b, f32x4 c) {
  return __builtin_amdgcn_mfma_f32_16x16x32_f16(a, b, c, 0, 0, 0);
}
__device__ __forceinline__ unsigned pkh(float a, float b) {
  union { __half2 h2; unsigned u; } x;
  x.h2 = __floats2half2_rn(a, b);
  return x.u;
}
__device__ __forceinline__ unsigned pkr(float a, float b) {
  return pkh(fmaxf(a, 0.f), fmaxf(b, 0.f));
}

#define SBAR __builtin_amdgcn_sched_barrier(0)
// wait lgkmcnt(n) only (vmcnt=63, expcnt=7)
#define LGKM_WAIT(n) __builtin_amdgcn_s_waitcnt(0xC07F | ((n) << 8))
#define ENDBAR(R)                                                              \
  do {                                                                         \
    SBAR;                                                                      \
    LGKM_WAIT(R);                                                              \
    __builtin_amdgcn_s_barrier();                                              \
    SBAR;                                                                      \
  } while (0)

// ring-16 slot helpers (compile-time for constant PB,U; i0 = 4J so 4*i0 = 0 mod 16)
#define SW16(PB, U)  ((4 * (PB) + (U)) & 15)
#define SR16(PB, U)  ((4 * (PB) + (U) + 12) & 15)
// wC head-item slot (item tau-1 at step tau = 4i-32+U): (4PB+U+15)&15
#define SWAO(PB, U)  ((4 * (PB) + (U) + 15) & 15)
// wS pre-read slot (at interval j for items 4j-37+U): (4PB+U+11)&15
#define SRAO(PB, U)  ((4 * (PB) + (U) + 11) & 15)

struct WP { const float *wih0,*whh0,*wih1,*whh1,*wih2,*whh2,*wout; };

// Concatenated zero-padded weight views:
//  L0 (K=32): k<24 -> W_hh0[m][k], k in [28,32) -> W_ih0[m][k-28]
//  L1 (K=96): k<24 -> W_ih1[m][k], k in [32,80) -> W_hh1[m][k-32]
//  L2 (K=96): k<48 -> W_ih2[m][k], k in [64,88) -> W_hh2[m][k-64]
//  L3 (K=32): k<24 -> W_out[m][k], m<2
__device__ float wcat(int layer, int m, int k, const WP& P) {
  if (layer == 0) {
    if (m < 24) {
      if (k < 24) return P.whh0[m * 24 + k];
      if (k >= 28 && k < 32) return P.wih0[m * 4 + (k - 28)];
    }
    return 0.f;
  } else if (layer == 1) {
    if (m < 48) {
      if (k < 24) return P.wih1[m * 24 + k];
      if (k >= 32 && k < 80) return P.whh1[m * 48 + (k - 32)];
    }
    return 0.f;
  } else if (layer == 2) {
    if (m < 24) {
      if (k < 48) return P.wih2[m * 48 + k];
      if (k >= 64 && k < 88) return P.whh2[m * 24 + (k - 64)];
    }
    return 0.f;
  } else {
    if (m < 2 && k < 24) return P.wout[m * 24 + k];
    return 0.f;
  }
}

__device__ f16x8 afrag(int layer, int mt, int kc, const WP& P) {
  int m  = mt * 16 + (threadIdx.x & 15);
  int kb = kc * 32 + 4 * ((threadIdx.x >> 4) & 3);
  f16x8 r;
#pragma unroll
  for (int j = 0; j < 4; ++j) r[j] = (_Float16)wcat(layer, m, kb + j, P);
#pragma unroll
  for (int j = 0; j < 4; ++j) r[4 + j] = (_Float16)wcat(layer, m, kb + 16 + j, P);
  return r;
}

__device__ f32x4 cfrag(const float* b1, const float* b2, int mt, int nvalid) {
  int qq = (threadIdx.x >> 4) & 3;
  f32x4 r;
#pragma unroll
  for (int i = 0; i < 4; ++i) {
    int m = mt * 16 + 4 * qq + i;
    float v = 0.f;
    if (m < nvalid) { v = b1[m]; if (b2) v += b2[m]; }
    r[i] = v;
  }
  return r;
}

__global__ void __launch_bounds__(512)
rnn3_p8r12(const float* __restrict__ x,
           const float* __restrict__ wih0, const float* __restrict__ whh0,
           const float* __restrict__ bih0, const float* __restrict__ bhh0,
           const float* __restrict__ wih1, const float* __restrict__ whh1,
           const float* __restrict__ bih1, const float* __restrict__ bhh1,
           const float* __restrict__ wih2, const float* __restrict__ whh2,
           const float* __restrict__ bih2, const float* __restrict__ bhh2,
           const float* __restrict__ wout, const float* __restrict__ bout,
           float* __restrict__ out) {
  __shared__ uint4  sH1[16][64];      // h1 packs               16 KB
  __shared__ f32x4  sP1[16][3][64];   // partial1 f32           48 KB
  __shared__ uint4  sH2a[16][64];     // h2[0:32] packs         16 KB
  __shared__ uint2  sH2b[16][64];     // h2[32:48] packs         8 KB
  __shared__ f32x4  sP2a[16][64];     // partial2 mt0 f32       16 KB
  __shared__ f32x4  sP2b[16][64];     // partial2 mt1 f32       16 KB
  __shared__ float2 sAO[16][16];      // head outputs            2 KB

  const int tid  = threadIdx.x;
  const int wid  = tid >> 6;
  const int lane = tid & 63;
  const int c = lane & 15;
  const int q = lane >> 4;
  const int b0 = blockIdx.x * 16;

  WP P{wih0, whh0, wih1, whh1, wih2, whh2, wout};
  const float4* x4 = (const float4*)x;
  float2*       o2 = (float2*)out;

  const int NJ = 35;  // 140 intervals, i = 0..139

  if (wid == 0) {
    // ===== wA: h1 recurrence (2 MFMA/step), items t = 4i+U, i in [0,127] =====
    f16x8 A00 = afrag(0, 0, 0, P), A01 = afrag(0, 1, 0, P);
    f32x4 C00 = cfrag(bih0, bhh0, 0, 24), C01 = cfrag(bih0, bhh0, 1, 24);
    float4 xb[16];
#pragma unroll
    for (int s = 0; s < 16; ++s) xb[s] = x4[(size_t)s * NBAT + b0 + c];
    unsigned fa0 = 0u, fa1 = 0u, fa2 = 0u, fa3 = 0u;  // pure h1 packs

#define A_STEP(PB, U)                                                          \
    {                                                                          \
      float4 xs = xb[SW16(PB, U)];                                             \
      BFrag FAu;                                                               \
      FAu.u[0] = fa0; FAu.u[1] = fa1;                                          \
      FAu.u[2] = (q == 3) ? pkh(xs.x, xs.y) : fa2;                             \
      FAu.u[3] = (q == 3) ? pkh(xs.z, xs.w) : fa3;                             \
      f32x4 a10 = MF(A00, FAu.h, C00);                                         \
      f32x4 a11 = MF(A01, FAu.h, C01);                                         \
      {                                                                        \
        int t = 4 * i + (U);                                                   \
        int tn = (t + 16 < TSEQ) ? t + 16 : TSEQ - 1;                          \
        xb[SW16(PB, U)] = x4[(size_t)tn * NBAT + b0 + c];                      \
      }                                                                        \
      fa0 = pkr(a10[0], a10[1]); fa1 = pkr(a10[2], a10[3]);                    \
      fa2 = pkr(a11[0], a11[1]); fa3 = pkr(a11[2], a11[3]);                    \
      sH1[SW16(PB, U)][lane] = make_uint4(fa0, fa1, fa2, fa3);                 \
    }
#define A_BODY(PB)                                                             \
    {                                                                          \
      int i = i0 + (PB);                                                       \
      if (i <= 127) { A_STEP(PB, 0) A_STEP(PB, 1) A_STEP(PB, 2) A_STEP(PB, 3) }\
      ENDBAR(0);                                                               \
    }
#pragma unroll 1
    for (int J = 0; J < NJ; ++J) {
      int i0 = 4 * J;
      A_BODY(0) A_BODY(1) A_BODY(2) A_BODY(3)
    }
#undef A_BODY
#undef A_STEP

  } else if (wid == 1 || wid == 2) {
    // == wD (mt0,mt1) / wH (mt2): partial1(tau), tau = 4i-8+U, i in [2,129] ==
    const bool isD = (wid == 1);
    f16x8 W0 = afrag(1, isD ? 0 : 2, 0, P);
    f16x8 W1 = isD ? afrag(1, 1, 0, P) : W0;
    f32x4 Cb0 = cfrag(bih1, bhh1, isD ? 0 : 2, 48);
    f32x4 Cb1 = isD ? cfrag(bih1, bhh1, 1, 48) : Cb0;
    uint4 bufA[4], bufB[4];
#pragma unroll
    for (int s = 0; s < 4; ++s) { bufA[s] = make_uint4(0u,0u,0u,0u); bufB[s] = make_uint4(0u,0u,0u,0u); }

#define D_STEP(PB, U, CUR)                                                     \
    {                                                                          \
      BFrag FAu;                                                               \
      FAu.u[0] = CUR[U].x; FAu.u[1] = CUR[U].y;                                \
      FAu.u[2] = CUR[U].z; FAu.u[3] = CUR[U].w;                                \
      f32x4 p0 = MF(W0, FAu.h, Cb0);                                           \
      if (isD) {                                                               \
        f32x4 p1 = MF(W1, FAu.h, Cb1);                                         \
        sP1[SW16(PB, U)][0][lane] = p0;                                        \
        sP1[SW16(PB, U)][1][lane] = p1;                                        \
      } else {                                                                 \
        sP1[SW16(PB, U)][2][lane] = p0;                                        \
      }                                                                        \
    }
#define D_BODY(PB, CUR, NXT)                                                   \
    {                                                                          \
      int i = i0 + (PB);                                                       \
      if (i >= 2 && i <= 129) {                                                \
        D_STEP(PB, 0, CUR) D_STEP(PB, 1, CUR)                                  \
        D_STEP(PB, 2, CUR) D_STEP(PB, 3, CUR)                                  \
      }                                                                        \
      SBAR;                                                                    \
      NXT[0] = sH1[SR16(PB, 0)][lane];                                         \
      NXT[1] = sH1[SR16(PB, 1)][lane];                                         \
      NXT[2] = sH1[SR16(PB, 2)][lane];                                         \
      NXT[3] = sH1[SR16(PB, 3)][lane];                                         \
      ENDBAR(4);                                                               \
    }
#pragma unroll 1
    for (int J = 0; J < NJ; ++J) {
      int i0 = 4 * J;
      D_BODY(0, bufA, bufB) D_BODY(1, bufB, bufA)
      D_BODY(2, bufA, bufB) D_BODY(3, bufB, bufA)
    }
#undef D_BODY
#undef D_STEP

  } else if (wid == 3) {
    // ===== wB: h2 recurrence (6 MFMA/step), items t = 4i-16+U, i in [4,131] =====
    // wid3 shares its SIMD with wid7 (store-only, 0 MFMA): exclusive matrix pipe.
    f16x8 A1c1[3], A1c2[3];
#pragma unroll
    for (int mt = 0; mt < 3; ++mt) {
      A1c1[mt] = afrag(1, mt, 1, P);
      A1c2[mt] = afrag(1, mt, 2, P);
    }
    const f32x4 Z4 = {0.f, 0.f, 0.f, 0.f};
    unsigned fb0 = 0u, fb1 = 0u, fb2 = 0u, fb3 = 0u, fc0 = 0u, fc1 = 0u;
    f32x4 pA[4][3], pB[4][3];
#pragma unroll
    for (int s = 0; s < 4; ++s)
#pragma unroll
      for (int m = 0; m < 3; ++m) { pA[s][m] = Z4; pB[s][m] = Z4; }

#define B_STEP(PB, U, CUR)                                                     \
    {                                                                          \
      BFrag FBu, FCu;                                                          \
      FBu.u[0] = fb0; FBu.u[1] = fb1; FBu.u[2] = fb2; FBu.u[3] = fb3;          \
      FCu.u[0] = fc0; FCu.u[1] = fc1; FCu.u[2] = 0u; FCu.u[3] = 0u;            \
      f32x4 aA0 = MF(A1c1[0], FBu.h, CUR[U][0]);                               \
      f32x4 aA1 = MF(A1c1[1], FBu.h, CUR[U][1]);                               \
      f32x4 aA2 = MF(A1c1[2], FBu.h, CUR[U][2]);                               \
      f32x4 aB0 = MF(A1c2[0], FCu.h, Z4);                                      \
      f32x4 aB1 = MF(A1c2[1], FCu.h, Z4);                                      \
      f32x4 aB2 = MF(A1c2[2], FCu.h, Z4);                                      \
      f32x4 s0 = aA0 + aB0, s1 = aA1 + aB1, s2 = aA2 + aB2;                    \
      fb0 = pkr(s0[0], s0[1]); fb1 = pkr(s0[2], s0[3]);                        \
      fb2 = pkr(s1[0], s1[1]); fb3 = pkr(s1[2], s1[3]);                        \
      fc0 = pkr(s2[0], s2[1]); fc1 = pkr(s2[2], s2[3]);                        \
      sH2a[SW16(PB, U)][lane] = make_uint4(fb0, fb1, fb2, fb3);                \
      sH2b[SW16(PB, U)][lane] = make_uint2(fc0, fc1);                          \
    }
#define B_BODY(PB, CUR, NXT)                                                   \
    {                                                                          \
      int i = i0 + (PB);                                                       \
      if (i >= 4 && i <= 131) {                                                \
        B_STEP(PB, 0, CUR) B_STEP(PB, 1, CUR)                                  \
        B_STEP(PB, 2, CUR) B_STEP(PB, 3, CUR)                                  \
      }                                                                        \
      SBAR;                                                                    \
      NXT[0][0] = sP1[SR16(PB, 0)][0][lane];                                   \
      NXT[0][1] = sP1[SR16(PB, 0)][1][lane];                                   \
      NXT[0][2] = sP1[SR16(PB, 0)][2][lane];                                   \
      NXT[1][0] = sP1[SR16(PB, 1)][0][lane];                                   \
      NXT[1][1] = sP1[SR16(PB, 1)][1][lane];                                   \
      NXT[1][2] = sP1[SR16(PB, 1)][2][lane];                                   \
      NXT[2][0] = sP1[SR16(PB, 2)][0][lane];                                   \
      NXT[2][1] = sP1[SR16(PB, 2)][1][lane];                                   \
      NXT[2][2] = sP1[SR16(PB, 2)][2][lane];                                   \
      NXT[3][0] = sP1[SR16(PB, 3)][0][lane];                                   \
      NXT[3][1] = sP1[SR16(PB, 3)][1][lane];                                   \
      NXT[3][2] = sP1[SR16(PB, 3)][2][lane];                                   \
      ENDBAR(12);                                                              \
    }
#pragma unroll 1
    for (int J = 0; J < NJ; ++J) {
      int i0 = 4 * J;
      B_BODY(0, pA, pB) B_BODY(1, pB, pA) B_BODY(2, pA, pB) B_BODY(3, pB, pA)
    }
#undef B_BODY
#undef B_STEP

  } else if (wid == 4 || wid == 5) {
    // == wE (mt0) / wF (mt1): partial2(tau), tau = 4i-24+U, i in [6,133] ==
    const int mt = (wid == 4) ? 0 : 1;
    f16x8 W0 = afrag(2, mt, 0, P), W1 = afrag(2, mt, 1, P);
    f32x4 Cb = cfrag(bih2, bhh2, mt, 24);
    uint4 haA[4], haB[4];
    uint2 hbA[4], hbB[4];
#pragma unroll
    for (int s = 0; s < 4; ++s) {
      haA[s] = make_uint4(0u,0u,0u,0u); haB[s] = make_uint4(0u,0u,0u,0u);
      hbA[s] = make_uint2(0u,0u);       hbB[s] = make_uint2(0u,0u);
    }

#define E_STEP(PB, U, CA, CB)                                                  \
    {                                                                          \
      BFrag FBu, FCu;                                                          \
      FBu.u[0] = CA[U].x; FBu.u[1] = CA[U].y;                                  \
      FBu.u[2] = CA[U].z; FBu.u[3] = CA[U].w;                                  \
      FCu.u[0] = CB[U].x; FCu.u[1] = CB[U].y;                                  \
      FCu.u[2] = 0u; FCu.u[3] = 0u;                                            \
      f32x4 p = MF(W0, FBu.h, Cb);                                             \
      p = MF(W1, FCu.h, p);                                                    \
      if (mt == 0) sP2a[SW16(PB, U)][lane] = p;                                \
      else         sP2b[SW16(PB, U)][lane] = p;                                \
    }
#define E_BODY(PB, CA, CB, NA, NB)                                             \
    {                                                                          \
      int i = i0 + (PB);                                                       \
      if (i >= 6 && i <= 133) {                                                \
        E_STEP(PB, 0, CA, CB) E_STEP(PB, 1, CA, CB)                            \
        E_STEP(PB, 2, CA, CB) E_STEP(PB, 3, CA, CB)                            \
      }                                                                        \
      SBAR;                                                                    \
      NA[0] = sH2a[SR16(PB, 0)][lane];                                         \
      NA[1] = sH2a[SR16(PB, 1)][lane];                                         \
      NA[2] = sH2a[SR16(PB, 2)][lane];                                         \
      NA[3] = sH2a[SR16(PB, 3)][lane];                                         \
      NB[0] = sH2b[SR16(PB, 0)][lane];                                         \
      NB[1] = sH2b[SR16(PB, 1)][lane];                                         \
      NB[2] = sH2b[SR16(PB, 2)][lane];                                         \
      NB[3] = sH2b[SR16(PB, 3)][lane];                                         \
      ENDBAR(8);                                                               \
    }
#pragma unroll 1
    for (int J = 0; J < NJ; ++J) {
      int i0 = 4 * J;
      E_BODY(0, haA, hbA, haB, hbB) E_BODY(1, haB, hbB, haA, hbA)
      E_BODY(2, haA, hbA, haB, hbB) E_BODY(3, haB, hbB, haA, hbA)
    }
#undef E_BODY
#undef E_STEP

  } else if (wid == 6) {
    // ===== wC: h3 recurrence + head, steps tau = 4i-32+U, i in [8,136] =====
    // head(tau-1) uses previous step's fd packs (in-register, no LDS hop);
    // i = 136 runs only to flush head(511) (its recurrence tail is garbage
    // and unconsumed).
    f16x8 A2c2m0 = afrag(2, 0, 2, P), A2c2m1 = afrag(2, 1, 2, P);
    f16x8 A3 = afrag(3, 0, 0, P);
    f32x4 C3 = cfrag(bout, nullptr, 0, 2);
    unsigned fd0 = 0u, fd1 = 0u, fd2 = 0u, fd3 = 0u;
    const f32x4 Z4 = {0.f, 0.f, 0.f, 0.f};
    f32x4 paA[4], paB[4], pbA[4], pbB[4];
#pragma unroll
    for (int s = 0; s < 4; ++s) { paA[s] = Z4; paB[s] = Z4; pbA[s] = Z4; pbB[s] = Z4; }

#define C_STEP(PB, U, CA, CB)                                                  \
    {                                                                          \
      BFrag FDu;                                                               \
      FDu.u[0] = fd0; FDu.u[1] = fd1; FDu.u[2] = fd2; FDu.u[3] = fd3;          \
      f32x4 ao = MF(A3, FDu.h, C3);          /* head(tau-1) */                 \
      f32x4 a30 = MF(A2c2m0, FDu.h, CA[U]);                                    \
      f32x4 a31 = MF(A2c2m1, FDu.h, CB[U]);                                    \
      int th = 4 * i - 33 + (U);                                               \
      if (th >= 0 && th < TSEQ && q == 0)                                      \
        sAO[SWAO(PB, U)][c] = make_float2(ao[0], ao[1]);                       \
      fd0 = pkr(a30[0], a30[1]); fd1 = pkr(a30[2], a30[3]);                    \
      fd2 = pkr(a31[0], a31[1]); fd3 = pkr(a31[2], a31[3]);                    \
    }
#define C_BODY(PB, CA, CB, NA, NB)                                             \
    {                                                                          \
      int i = i0 + (PB);                                                       \
      if (i >= 8 && i <= 136) {                                                \
        C_STEP(PB, 0, CA, CB) C_STEP(PB, 1, CA, CB)                            \
        C_STEP(PB, 2, CA, CB) C_STEP(PB, 3, CA, CB)                            \
      }                                                                        \
      SBAR;                                                                    \
      NA[0] = sP2a[SR16(PB, 0)][lane];                                         \
      NA[1] = sP2a[SR16(PB, 1)][lane];                                         \
      NA[2] = sP2a[SR16(PB, 2)][lane];                                         \
      NA[3] = sP2a[SR16(PB, 3)][lane];                                         \
      NB[0] = sP2b[SR16(PB, 0)][lane];                                         \
      NB[1] = sP2b[SR16(PB, 1)][lane];                                         \
      NB[2] = sP2b[SR16(PB, 2)][lane];                                         \
      NB[3] = sP2b[SR16(PB, 3)][lane];                                         \
      ENDBAR(8);                                                               \
    }
#pragma unroll 1
    for (int J = 0; J < NJ; ++J) {
      int i0 = 4 * J;
      C_BODY(0, paA, pbA, paB, pbB) C_BODY(1, paB, pbB, paA, pbA)
      C_BODY(2, paA, pbA, paB, pbB) C_BODY(3, paB, pbB, paA, pbA)
    }
#undef C_BODY
#undef C_STEP

  } else {
    // ===== wS: store-only (0 MFMA), items t = 4j-41+U, j in [10,138] =====
    float2 aoA[4], aoB[4];
#pragma unroll
    for (int s = 0; s < 4; ++s) { aoA[s] = make_float2(0.f, 0.f); aoB[s] = make_float2(0.f, 0.f); }

#define S_STEP(PB, U, CUR)                                                     \
    {                                                                          \
      int t = 4 * i - 41 + (U);                                                \
      if (t >= 0 && t < TSEQ && q == 0)                                        \
        o2[(size_t)t * NBAT + b0 + c] = CUR[U];                                \
    }
#define S_BODY(PB, CUR, NXT)                                                   \
    {                                                                          \
      int i = i0 + (PB);                                                       \
      if (i >= 10 && i <= 138) {                                               \
        S_STEP(PB, 0, CUR) S_STEP(PB, 1, CUR)                                  \
        S_STEP(PB, 2, CUR) S_STEP(PB, 3, CUR)                                  \
      }                                                                        \
      SBAR;                                                                    \
      NXT[0] = sAO[SRAO(PB, 0)][c];                                            \
      NXT[1] = sAO[SRAO(PB, 1)][c];                                            \
      NXT[2] = sAO[SRAO(PB, 2)][c];                                            \
      NXT[3] = sAO[SRAO(PB, 3)][c];                                            \
      ENDBAR(4);                                                               \
    }
#pragma unroll 1
    for (int J = 0; J < NJ; ++J) {
      int i0 = 4 * J;
      S_BODY(0, aoA, aoB) S_BODY(1, aoB, aoA)
      S_BODY(2, aoA, aoB) S_BODY(3, aoB, aoA)
    }
#undef S_BODY
#undef S_STEP
  }
}

extern "C" void kernel_launch(void* const* d_in, const int* in_sizes, int n_in,
                              void* d_out, int out_size, void* d_ws, size_t ws_size,
                              hipStream_t stream) {
  const float* x    = (const float*)d_in[0];
  const float* wih0 = (const float*)d_in[1];
  const float* whh0 = (const float*)d_in[2];
  const float* bih0 = (const float*)d_in[3];
  const float* bhh0 = (const float*)d_in[4];
  const float* wih1 = (const float*)d_in[5];
  const float* whh1 = (const float*)d_in[6];
  const float* bih1 = (const float*)d_in[7];
  const float* bhh1 = (const float*)d_in[8];
  const float* wih2 = (const float*)d_in[9];
  const float* whh2 = (const float*)d_in[10];
  const float* bih2 = (const float*)d_in[11];
  const float* bhh2 = (const float*)d_in[12];
  const float* wout = (const float*)d_in[13];
  const float* bout = (const float*)d_in[14];
  float* out = (float*)d_out;

  rnn3_p8r12<<<dim3(NBAT / 16), dim3(512), 0, stream>>>(
      x, wih0, whh0, bih0, bhh0, wih1, whh1, bih1, bhh1,
      wih2, whh2, bih2, bhh2, wout, bout, out);
}

// Round 13
// 81.916 us; speedup vs baseline: 1.0366x; 1.0366x over previous
//
#include <hip/hip_runtime.h>
#include <hip/hip_fp16.h>

// Fused 3-layer ReLU-RNN + linear head, MI355X (gfx950).
// T=512, B=4096, IN=4, H1=24, H2=48, H3=24, OUT=2.
//
// ROUND 13: round-12 skeleton (8-wave uniform-lag forward pipeline, S=4
// steps/interval, ring-16 LDS, counted LGKM + raw s_barrier, pre-read one
// interval ahead, store-only wS). Fitted model from rounds 10/11:
// interval overhead ~80 cyc, critical wave (wB) ~343 cyc/step -> attack wB:
//  (1) wB's 4-step body is EXPLICITLY software-pipelined at sub-step
//      granularity: aA(u+1) [needs only fb(u)+p1] issues between fb(u) and
//      fc(u) packs; aB(u+1) [needs fc(u)] after. Step u's fc path hides
//      under step u+1's aA MFMAs. Dataflow bit-identical, order exposed.
//  (2) h2 LDS writes moved out of the chain to the interval tail (consumers
//      read 2 intervals later; ENDBAR(12): 8 writes precede 12 pre-reads,
//      in-order DS retire => writes drained, reads in flight).
//  (3) packed relu via __builtin_elementwise_max on f16x2 (intrinsic, NOT
//      round-4's inline asm) saves 1 VALU per pack.
//  (4) wC issues recurrence MFMAs before the head MFMA.

#define TSEQ 512
#define NBAT 4096

typedef float    f32x4 __attribute__((ext_vector_type(4)));
typedef _Float16 f16x8 __attribute__((ext_vector_type(8)));
typedef _Float16 f16x2 __attribute__((ext_vector_type(2)));

union BFrag { f16x8 h; unsigned u[4]; };

__device__ __forceinline__ f32x4 MF(f16x8 a, f16x8 b, f32x4 c) {
  return __builtin_amdgcn_mfma_f32_16x16x32_f16(a, b, c, 0, 0, 0);
}
__device__ __forceinline__ unsigned pkh(float a, float b) {
  union { __half2 h2; unsigned u; } x;
  x.h2 = __floats2half2_rn(a, b);
  return x.u;
}
#if __has_builtin(__builtin_elementwise_max)
// relu applied in f16 after RN pack: relu(rn(x)) == rn(relu(x)) (mod +-0).
__device__ __forceinline__ unsigned pkr(float a, float b) {
  union { __half2 h2; f16x2 f; unsigned u; } x;
  x.h2 = __floats2half2_rn(a, b);
  f16x2 z = {(_Float16)0.f, (_Float16)0.f};
  x.f = __builtin_elementwise_max(x.f, z);
  return x.u;
}
#else
__device__ __forceinline__ unsigned pkr(float a, float b) {
  return pkh(fmaxf(a, 0.f), fmaxf(b, 0.f));
}
#endif

#define SBAR __builtin_amdgcn_sched_barrier(0)
// wait lgkmcnt(n) only (vmcnt=63, expcnt=7)
#define LGKM_WAIT(n) __builtin_amdgcn_s_waitcnt(0xC07F | ((n) << 8))
#define ENDBAR(R)                                                              \
  do {                                                                         \
    SBAR;                                                                      \
    LGKM_WAIT(R);                                                              \
    __builtin_amdgcn_s_barrier();                                              \
    SBAR;                                                                      \
  } while (0)

// ring-16 slot helpers (compile-time for constant PB,U; i0 = 4J so 4*i0 = 0 mod 16)
#define SW16(PB, U)  ((4 * (PB) + (U)) & 15)
#define SR16(PB, U)  ((4 * (PB) + (U) + 12) & 15)
// wC head-item slot (item tau-1 at step tau = 4i-32+U): (4PB+U+15)&15
#define SWAO(PB, U)  ((4 * (PB) + (U) + 15) & 15)
// wS pre-read slot (at interval j for items 4j-37+U): (4PB+U+11)&15
#define SRAO(PB, U)  ((4 * (PB) + (U) + 11) & 15)

struct WP { const float *wih0,*whh0,*wih1,*whh1,*wih2,*whh2,*wout; };

// Concatenated zero-padded weight views:
//  L0 (K=32): k<24 -> W_hh0[m][k], k in [28,32) -> W_ih0[m][k-28]
//  L1 (K=96): k<24 -> W_ih1[m][k], k in [32,80) -> W_hh1[m][k-32]
//  L2 (K=96): k<48 -> W_ih2[m][k], k in [64,88) -> W_hh2[m][k-64]
//  L3 (K=32): k<24 -> W_out[m][k], m<2
__device__ float wcat(int layer, int m, int k, const WP& P) {
  if (layer == 0) {
    if (m < 24) {
      if (k < 24) return P.whh0[m * 24 + k];
      if (k >= 28 && k < 32) return P.wih0[m * 4 + (k - 28)];
    }
    return 0.f;
  } else if (layer == 1) {
    if (m < 48) {
      if (k < 24) return P.wih1[m * 24 + k];
      if (k >= 32 && k < 80) return P.whh1[m * 48 + (k - 32)];
    }
    return 0.f;
  } else if (layer == 2) {
    if (m < 24) {
      if (k < 48) return P.wih2[m * 48 + k];
      if (k >= 64 && k < 88) return P.whh2[m * 24 + (k - 64)];
    }
    return 0.f;
  } else {
    if (m < 2 && k < 24) return P.wout[m * 24 + k];
    return 0.f;
  }
}

__device__ f16x8 afrag(int layer, int mt, int kc, const WP& P) {
  int m  = mt * 16 + (threadIdx.x & 15);
  int kb = kc * 32 + 4 * ((threadIdx.x >> 4) & 3);
  f16x8 r;
#pragma unroll
  for (int j = 0; j < 4; ++j) r[j] = (_Float16)wcat(layer, m, kb + j, P);
#pragma unroll
  for (int j = 0; j < 4; ++j) r[4 + j] = (_Float16)wcat(layer, m, kb + 16 + j, P);
  return r;
}

__device__ f32x4 cfrag(const float* b1, const float* b2, int mt, int nvalid) {
  int qq = (threadIdx.x >> 4) & 3;
  f32x4 r;
#pragma unroll
  for (int i = 0; i < 4; ++i) {
    int m = mt * 16 + 4 * qq + i;
    float v = 0.f;
    if (m < nvalid) { v = b1[m]; if (b2) v += b2[m]; }
    r[i] = v;
  }
  return r;
}

__global__ void __launch_bounds__(512)
rnn3_p8r13(const float* __restrict__ x,
           const float* __restrict__ wih0, const float* __restrict__ whh0,
           const float* __restrict__ bih0, const float* __restrict__ bhh0,
           const float* __restrict__ wih1, const float* __restrict__ whh1,
           const float* __restrict__ bih1, const float* __restrict__ bhh1,
           const float* __restrict__ wih2, const float* __restrict__ whh2,
           const float* __restrict__ bih2, const float* __restrict__ bhh2,
           const float* __restrict__ wout, const float* __restrict__ bout,
           float* __restrict__ out) {
  __shared__ uint4  sH1[16][64];      // h1 packs               16 KB
  __shared__ f32x4  sP1[16][3][64];   // partial1 f32           48 KB
  __shared__ uint4  sH2a[16][64];     // h2[0:32] packs         16 KB
  __shared__ uint2  sH2b[16][64];     // h2[32:48] packs         8 KB
  __shared__ f32x4  sP2a[16][64];     // partial2 mt0 f32       16 KB
  __shared__ f32x4  sP2b[16][64];     // partial2 mt1 f32       16 KB
  __shared__ float2 sAO[16][16];      // head outputs            2 KB

  const int tid  = threadIdx.x;
  const int wid  = tid >> 6;
  const int lane = tid & 63;
  const int c = lane & 15;
  const int q = lane >> 4;
  const int b0 = blockIdx.x * 16;

  WP P{wih0, whh0, wih1, whh1, wih2, whh2, wout};
  const float4* x4 = (const float4*)x;
  float2*       o2 = (float2*)out;

  const int NJ = 35;  // 140 intervals, i = 0..139

  if (wid == 0) {
    // ===== wA: h1 recurrence (2 MFMA/step), items t = 4i+U, i in [0,127] =====
    f16x8 A00 = afrag(0, 0, 0, P), A01 = afrag(0, 1, 0, P);
    f32x4 C00 = cfrag(bih0, bhh0, 0, 24), C01 = cfrag(bih0, bhh0, 1, 24);
    float4 xb[16];
#pragma unroll
    for (int s = 0; s < 16; ++s) xb[s] = x4[(size_t)s * NBAT + b0 + c];
    unsigned fa0 = 0u, fa1 = 0u, fa2 = 0u, fa3 = 0u;  // pure h1 packs

#define A_STEP(PB, U)                                                          \
    {                                                                          \
      float4 xs = xb[SW16(PB, U)];                                             \
      BFrag FAu;                                                               \
      FAu.u[0] = fa0; FAu.u[1] = fa1;                                          \
      FAu.u[2] = (q == 3) ? pkh(xs.x, xs.y) : fa2;                             \
      FAu.u[3] = (q == 3) ? pkh(xs.z, xs.w) : fa3;                             \
      f32x4 a10 = MF(A00, FAu.h, C00);                                         \
      f32x4 a11 = MF(A01, FAu.h, C01);                                         \
      {                                                                        \
        int t = 4 * i + (U);                                                   \
        int tn = (t + 16 < TSEQ) ? t + 16 : TSEQ - 1;                          \
        xb[SW16(PB, U)] = x4[(size_t)tn * NBAT + b0 + c];                      \
      }                                                                        \
      fa0 = pkr(a10[0], a10[1]); fa1 = pkr(a10[2], a10[3]);                    \
      fa2 = pkr(a11[0], a11[1]); fa3 = pkr(a11[2], a11[3]);                    \
      sH1[SW16(PB, U)][lane] = make_uint4(fa0, fa1, fa2, fa3);                 \
    }
#define A_BODY(PB)                                                             \
    {                                                                          \
      int i = i0 + (PB);                                                       \
      if (i <= 127) { A_STEP(PB, 0) A_STEP(PB, 1) A_STEP(PB, 2) A_STEP(PB, 3) }\
      ENDBAR(0);                                                               \
    }
#pragma unroll 1
    for (int J = 0; J < NJ; ++J) {
      int i0 = 4 * J;
      A_BODY(0) A_BODY(1) A_BODY(2) A_BODY(3)
    }
#undef A_BODY
#undef A_STEP

  } else if (wid == 1 || wid == 2) {
    // == wD (mt0,mt1) / wH (mt2): partial1(tau), tau = 4i-8+U, i in [2,129] ==
    const bool isD = (wid == 1);
    f16x8 W0 = afrag(1, isD ? 0 : 2, 0, P);
    f16x8 W1 = isD ? afrag(1, 1, 0, P) : W0;
    f32x4 Cb0 = cfrag(bih1, bhh1, isD ? 0 : 2, 48);
    f32x4 Cb1 = isD ? cfrag(bih1, bhh1, 1, 48) : Cb0;
    uint4 bufA[4], bufB[4];
#pragma unroll
    for (int s = 0; s < 4; ++s) { bufA[s] = make_uint4(0u,0u,0u,0u); bufB[s] = make_uint4(0u,0u,0u,0u); }

#define D_STEP(PB, U, CUR)                                                     \
    {                                                                          \
      BFrag FAu;                                                               \
      FAu.u[0] = CUR[U].x; FAu.u[1] = CUR[U].y;                                \
      FAu.u[2] = CUR[U].z; FAu.u[3] = CUR[U].w;                                \
      f32x4 p0 = MF(W0, FAu.h, Cb0);                                           \
      if (isD) {                                                               \
        f32x4 p1 = MF(W1, FAu.h, Cb1);                                         \
        sP1[SW16(PB, U)][0][lane] = p0;                                        \
        sP1[SW16(PB, U)][1][lane] = p1;                                        \
      } else {                                                                 \
        sP1[SW16(PB, U)][2][lane] = p0;                                        \
      }                                                                        \
    }
#define D_BODY(PB, CUR, NXT)                                                   \
    {                                                                          \
      int i = i0 + (PB);                                                       \
      if (i >= 2 && i <= 129) {                                                \
        D_STEP(PB, 0, CUR) D_STEP(PB, 1, CUR)                                  \
        D_STEP(PB, 2, CUR) D_STEP(PB, 3, CUR)                                  \
      }                                                                        \
      SBAR;                                                                    \
      NXT[0] = sH1[SR16(PB, 0)][lane];                                         \
      NXT[1] = sH1[SR16(PB, 1)][lane];                                         \
      NXT[2] = sH1[SR16(PB, 2)][lane];                                         \
      NXT[3] = sH1[SR16(PB, 3)][lane];                                         \
      ENDBAR(4);                                                               \
    }
#pragma unroll 1
    for (int J = 0; J < NJ; ++J) {
      int i0 = 4 * J;
      D_BODY(0, bufA, bufB) D_BODY(1, bufB, bufA)
      D_BODY(2, bufA, bufB) D_BODY(3, bufB, bufA)
    }
#undef D_BODY
#undef D_STEP

  } else if (wid == 3) {
    // ===== wB: h2 recurrence, items t = 4i-16+U, i in [4,131] =====
    // Explicitly software-pipelined 4-step body: fc(u) packs and aB(u+1)
    // issue hide under aA(u+1); LDS writes deferred to interval tail.
    f16x8 A1c1[3], A1c2[3];
#pragma unroll
    for (int mt = 0; mt < 3; ++mt) {
      A1c1[mt] = afrag(1, mt, 1, P);
      A1c2[mt] = afrag(1, mt, 2, P);
    }
    const f32x4 Z4 = {0.f, 0.f, 0.f, 0.f};
    unsigned fb0 = 0u, fb1 = 0u, fb2 = 0u, fb3 = 0u, fc0 = 0u, fc1 = 0u;
    f32x4 pA[4][3], pB[4][3];
#pragma unroll
    for (int s = 0; s < 4; ++s)
#pragma unroll
      for (int m = 0; m < 3; ++m) { pA[s][m] = Z4; pB[s][m] = Z4; }

#define B_QUAD(PB, CUR)                                                        \
    {                                                                          \
      BFrag F0, G0;                                                            \
      F0.u[0] = fb0; F0.u[1] = fb1; F0.u[2] = fb2; F0.u[3] = fb3;              \
      G0.u[0] = fc0; G0.u[1] = fc1; G0.u[2] = 0u; G0.u[3] = 0u;                \
      /* step 0 */                                                             \
      f32x4 a00 = MF(A1c1[0], F0.h, CUR[0][0]);                                \
      f32x4 a01 = MF(A1c1[1], F0.h, CUR[0][1]);                                \
      f32x4 a02 = MF(A1c1[2], F0.h, CUR[0][2]);                                \
      f32x4 b00 = MF(A1c2[0], G0.h, Z4);                                       \
      f32x4 b01 = MF(A1c2[1], G0.h, Z4);                                       \
      f32x4 b02 = MF(A1c2[2], G0.h, Z4);                                       \
      f32x4 s00 = a00 + b00, s01 = a01 + b01;                                  \
      unsigned h00 = pkr(s00[0], s00[1]), h01 = pkr(s00[2], s00[3]);           \
      unsigned h02 = pkr(s01[0], s01[1]), h03 = pkr(s01[2], s01[3]);           \
      BFrag F1; F1.u[0] = h00; F1.u[1] = h01; F1.u[2] = h02; F1.u[3] = h03;    \
      /* step 1 aA (hides step0 fc path) */                                    \
      f32x4 a10 = MF(A1c1[0], F1.h, CUR[1][0]);                                \
      f32x4 a11 = MF(A1c1[1], F1.h, CUR[1][1]);                                \
      f32x4 a12 = MF(A1c1[2], F1.h, CUR[1][2]);                                \
      f32x4 s02 = a02 + b02;                                                   \
      unsigned h04 = pkr(s02[0], s02[1]), h05 = pkr(s02[2], s02[3]);           \
      BFrag G1; G1.u[0] = h04; G1.u[1] = h05; G1.u[2] = 0u; G1.u[3] = 0u;      \
      f32x4 b10 = MF(A1c2[0], G1.h, Z4);                                       \
      f32x4 b11 = MF(A1c2[1], G1.h, Z4);                                       \
      f32x4 b12 = MF(A1c2[2], G1.h, Z4);                                       \
      f32x4 s10 = a10 + b10, s11 = a11 + b11;                                  \
      unsigned h10 = pkr(s10[0], s10[1]), h11 = pkr(s10[2], s10[3]);           \
      unsigned h12 = pkr(s11[0], s11[1]), h13 = pkr(s11[2], s11[3]);           \
      BFrag F2; F2.u[0] = h10; F2.u[1] = h11; F2.u[2] = h12; F2.u[3] = h13;    \
      /* step 2 aA */                                                          \
      f32x4 a20 = MF(A1c1[0], F2.h, CUR[2][0]);                                \
      f32x4 a21 = MF(A1c1[1], F2.h, CUR[2][1]);                                \
      f32x4 a22 = MF(A1c1[2], F2.h, CUR[2][2]);                                \
      f32x4 s12 = a12 + b12;                                                   \
      unsigned h14 = pkr(s12[0], s12[1]), h15 = pkr(s12[2], s12[3]);           \
      BFrag G2; G2.u[0] = h14; G2.u[1] = h15; G2.u[2] = 0u; G2.u[3] = 0u;      \
      f32x4 b20 = MF(A1c2[0], G2.h, Z4);                                       \
      f32x4 b21 = MF(A1c2[1], G2.h, Z4);                                       \
      f32x4 b22 = MF(A1c2[2], G2.h, Z4);                                       \
      f32x4 s20 = a20 + b20, s21 = a21 + b21;                                  \
      unsigned h20 = pkr(s20[0], s20[1]), h21 = pkr(s20[2], s20[3]);           \
      unsigned h22 = pkr(s21[0], s21[1]), h23 = pkr(s21[2], s21[3]);           \
      BFrag F3; F3.u[0] = h20; F3.u[1] = h21; F3.u[2] = h22; F3.u[3] = h23;    \
      /* step 3 aA */                                                          \
      f32x4 a30 = MF(A1c1[0], F3.h, CUR[3][0]);                                \
      f32x4 a31 = MF(A1c1[1], F3.h, CUR[3][1]);                                \
      f32x4 a32 = MF(A1c1[2], F3.h, CUR[3][2]);                                \
      f32x4 s22 = a22 + b22;                                                   \
      unsigned h24 = pkr(s22[0], s22[1]), h25 = pkr(s22[2], s22[3]);           \
      BFrag G3; G3.u[0] = h24; G3.u[1] = h25; G3.u[2] = 0u; G3.u[3] = 0u;      \
      f32x4 b30 = MF(A1c2[0], G3.h, Z4);                                       \
      f32x4 b31 = MF(A1c2[1], G3.h, Z4);                                       \
      f32x4 b32 = MF(A1c2[2], G3.h, Z4);                                       \
      f32x4 s30 = a30 + b30, s31 = a31 + b31, s32 = a32 + b32;                 \
      fb0 = pkr(s30[0], s30[1]); fb1 = pkr(s30[2], s30[3]);                    \
      fb2 = pkr(s31[0], s31[1]); fb3 = pkr(s31[2], s31[3]);                    \
      fc0 = pkr(s32[0], s32[1]); fc1 = pkr(s32[2], s32[3]);                    \
      /* deferred LDS writes (out of the chain) */                             \
      sH2a[SW16(PB, 0)][lane] = make_uint4(h00, h01, h02, h03);                \
      sH2b[SW16(PB, 0)][lane] = make_uint2(h04, h05);                          \
      sH2a[SW16(PB, 1)][lane] = make_uint4(h10, h11, h12, h13);                \
      sH2b[SW16(PB, 1)][lane] = make_uint2(h14, h15);                          \
      sH2a[SW16(PB, 2)][lane] = make_uint4(h20, h21, h22, h23);                \
      sH2b[SW16(PB, 2)][lane] = make_uint2(h24, h25);                          \
      sH2a[SW16(PB, 3)][lane] = make_uint4(fb0, fb1, fb2, fb3);                \
      sH2b[SW16(PB, 3)][lane] = make_uint2(fc0, fc1);                          \
    }
#define B_BODY(PB, CUR, NXT)                                                   \
    {                                                                          \
      int i = i0 + (PB);                                                       \
      if (i >= 4 && i <= 131) { B_QUAD(PB, CUR) }                              \
      SBAR;                                                                    \
      NXT[0][0] = sP1[SR16(PB, 0)][0][lane];                                   \
      NXT[0][1] = sP1[SR16(PB, 0)][1][lane];                                   \
      NXT[0][2] = sP1[SR16(PB, 0)][2][lane];                                   \
      NXT[1][0] = sP1[SR16(PB, 1)][0][lane];                                   \
      NXT[1][1] = sP1[SR16(PB, 1)][1][lane];                                   \
      NXT[1][2] = sP1[SR16(PB, 1)][2][lane];                                   \
      NXT[2][0] = sP1[SR16(PB, 2)][0][lane];                                   \
      NXT[2][1] = sP1[SR16(PB, 2)][1][lane];                                   \
      NXT[2][2] = sP1[SR16(PB, 2)][2][lane];                                   \
      NXT[3][0] = sP1[SR16(PB, 3)][0][lane];                                   \
      NXT[3][1] = sP1[SR16(PB, 3)][1][lane];                                   \
      NXT[3][2] = sP1[SR16(PB, 3)][2][lane];                                   \
      ENDBAR(12);                                                              \
    }
#pragma unroll 1
    for (int J = 0; J < NJ; ++J) {
      int i0 = 4 * J;
      B_BODY(0, pA, pB) B_BODY(1, pB, pA) B_BODY(2, pA, pB) B_BODY(3, pB, pA)
    }
#undef B_BODY
#undef B_QUAD

  } else if (wid == 4 || wid == 5) {
    // == wE (mt0) / wF (mt1): partial2(tau), tau = 4i-24+U, i in [6,133] ==
    const int mt = (wid == 4) ? 0 : 1;
    f16x8 W0 = afrag(2, mt, 0, P), W1 = afrag(2, mt, 1, P);
    f32x4 Cb = cfrag(bih2, bhh2, mt, 24);
    uint4 haA[4], haB[4];
    uint2 hbA[4], hbB[4];
#pragma unroll
    for (int s = 0; s < 4; ++s) {
      haA[s] = make_uint4(0u,0u,0u,0u); haB[s] = make_uint4(0u,0u,0u,0u);
      hbA[s] = make_uint2(0u,0u);       hbB[s] = make_uint2(0u,0u);
    }

#define E_STEP(PB, U, CA, CB)                                                  \
    {                                                                          \
      BFrag FBu, FCu;                                                          \
      FBu.u[0] = CA[U].x; FBu.u[1] = CA[U].y;                                  \
      FBu.u[2] = CA[U].z; FBu.u[3] = CA[U].w;                                  \
      FCu.u[0] = CB[U].x; FCu.u[1] = CB[U].y;                                  \
      FCu.u[2] = 0u; FCu.u[3] = 0u;                                            \
      f32x4 p = MF(W0, FBu.h, Cb);                                             \
      p = MF(W1, FCu.h, p);                                                    \
      if (mt == 0) sP2a[SW16(PB, U)][lane] = p;                                \
      else         sP2b[SW16(PB, U)][lane] = p;                                \
    }
#define E_BODY(PB, CA, CB, NA, NB)                                             \
    {                                                                          \
      int i = i0 + (PB);                                                       \
      if (i >= 6 && i <= 133) {                                                \
        E_STEP(PB, 0, CA, CB) E_STEP(PB, 1, CA, CB)                            \
        E_STEP(PB, 2, CA, CB) E_STEP(PB, 3, CA, CB)                            \
      }                                                                        \
      SBAR;                                                                    \
      NA[0] = sH2a[SR16(PB, 0)][lane];                                         \
      NA[1] = sH2a[SR16(PB, 1)][lane];                                         \
      NA[2] = sH2a[SR16(PB, 2)][lane];                                         \
      NA[3] = sH2a[SR16(PB, 3)][lane];                                         \
      NB[0] = sH2b[SR16(PB, 0)][lane];                                         \
      NB[1] = sH2b[SR16(PB, 1)][lane];                                         \
      NB[2] = sH2b[SR16(PB, 2)][lane];                                         \
      NB[3] = sH2b[SR16(PB, 3)][lane];                                         \
      ENDBAR(8);                                                               \
    }
#pragma unroll 1
    for (int J = 0; J < NJ; ++J) {
      int i0 = 4 * J;
      E_BODY(0, haA, hbA, haB, hbB) E_BODY(1, haB, hbB, haA, hbA)
      E_BODY(2, haA, hbA, haB, hbB) E_BODY(3, haB, hbB, haA, hbA)
    }
#undef E_BODY
#undef E_STEP

  } else if (wid == 6) {
    // ===== wC: h3 recurrence + head, steps tau = 4i-32+U, i in [8,136] =====
    // recurrence MFMAs issue before the head MFMA (head result consumed late).
    f16x8 A2c2m0 = afrag(2, 0, 2, P), A2c2m1 = afrag(2, 1, 2, P);
    f16x8 A3 = afrag(3, 0, 0, P);
    f32x4 C3 = cfrag(bout, nullptr, 0, 2);
    unsigned fd0 = 0u, fd1 = 0u, fd2 = 0u, fd3 = 0u;
    const f32x4 Z4 = {0.f, 0.f, 0.f, 0.f};
    f32x4 paA[4], paB[4], pbA[4], pbB[4];
#pragma unroll
    for (int s = 0; s < 4; ++s) { paA[s] = Z4; paB[s] = Z4; pbA[s] = Z4; pbB[s] = Z4; }

#define C_STEP(PB, U, CA, CB)                                                  \
    {                                                                          \
      BFrag FDu;                                                               \
      FDu.u[0] = fd0; FDu.u[1] = fd1; FDu.u[2] = fd2; FDu.u[3] = fd3;          \
      f32x4 a30 = MF(A2c2m0, FDu.h, CA[U]);                                    \
      f32x4 a31 = MF(A2c2m1, FDu.h, CB[U]);                                    \
      f32x4 ao = MF(A3, FDu.h, C3);          /* head(tau-1) */                 \
      int th = 4 * i - 33 + (U);                                               \
      if (th >= 0 && th < TSEQ && q == 0)                                      \
        sAO[SWAO(PB, U)][c] = make_float2(ao[0], ao[1]);                       \
      fd0 = pkr(a30[0], a30[1]); fd1 = pkr(a30[2], a30[3]);                    \
      fd2 = pkr(a31[0], a31[1]); fd3 = pkr(a31[2], a31[3]);                    \
    }
#define C_BODY(PB, CA, CB, NA, NB)                                             \
    {                                                                          \
      int i = i0 + (PB);                                                       \
      if (i >= 8 && i <= 136) {                                                \
        C_STEP(PB, 0, CA, CB) C_STEP(PB, 1, CA, CB)                            \
        C_STEP(PB, 2, CA, CB) C_STEP(PB, 3, CA, CB)                            \
      }                                                                        \
      SBAR;                                                                    \
      NA[0] = sP2a[SR16(PB, 0)][lane];                                         \
      NA[1] = sP2a[SR16(PB, 1)][lane];                                         \
      NA[2] = sP2a[SR16(PB, 2)][lane];                                         \
      NA[3] = sP2a[SR16(PB, 3)][lane];                                         \
      NB[0] = sP2b[SR16(PB, 0)][lane];                                         \
      NB[1] = sP2b[SR16(PB, 1)][lane];                                         \
      NB[2] = sP2b[SR16(PB, 2)][lane];                                         \
      NB[3] = sP2b[SR16(PB, 3)][lane];                                         \
      ENDBAR(8);                                                               \
    }
#pragma unroll 1
    for (int J = 0; J < NJ; ++J) {
      int i0 = 4 * J;
      C_BODY(0, paA, pbA, paB, pbB) C_BODY(1, paB, pbB, paA, pbA)
      C_BODY(2, paA, pbA, paB, pbB) C_BODY(3, paB, pbB, paA, pbA)
    }
#undef C_BODY
#undef C_STEP

  } else {
    // ===== wS: store-only (0 MFMA), items t = 4j-41+U, j in [10,138] =====
    float2 aoA[4], aoB[4];
#pragma unroll
    for (int s = 0; s < 4; ++s) { aoA[s] = make_float2(0.f, 0.f); aoB[s] = make_float2(0.f, 0.f); }

#define S_STEP(PB, U, CUR)                                                     \
    {                                                                          \
      int t = 4 * i - 41 + (U);                                                \
      if (t >= 0 && t < TSEQ && q == 0)                                        \
        o2[(size_t)t * NBAT + b0 + c] = CUR[U];                                \
    }
#define S_BODY(PB, CUR, NXT)                                                   \
    {                                                                          \
      int i = i0 + (PB);                                                       \
      if (i >= 10 && i <= 138) {                                               \
        S_STEP(PB, 0, CUR) S_STEP(PB, 1, CUR)                                  \
        S_STEP(PB, 2, CUR) S_STEP(PB, 3, CUR)                                  \
      }                                                                        \
      SBAR;                                                                    \
      NXT[0] = sAO[SRAO(PB, 0)][c];                                            \
      NXT[1] = sAO[SRAO(PB, 1)][c];                                            \
      NXT[2] = sAO[SRAO(PB, 2)][c];                                            \
      NXT[3] = sAO[SRAO(PB, 3)][c];                                            \
      ENDBAR(4);                                                               \
    }
#pragma unroll 1
    for (int J = 0; J < NJ; ++J) {
      int i0 = 4 * J;
      S_BODY(0, aoA, aoB) S_BODY(1, aoB, aoA)
      S_BODY(2, aoA, aoB) S_BODY(3, aoB, aoA)
    }
#undef S_BODY
#undef S_STEP
  }
}

extern "C" void kernel_launch(void* const* d_in, const int* in_sizes, int n_in,
                              void* d_out, int out_size, void* d_ws, size_t ws_size,
                              hipStream_t stream) {
  const float* x    = (const float*)d_in[0];
  const float* wih0 = (const float*)d_in[1];
  const float* whh0 = (const float*)d_in[2];
  const float* bih0 = (const float*)d_in[3];
  const float* bhh0 = (const float*)d_in[4];
  const float* wih1 = (const float*)d_in[5];
  const float* whh1 = (const float*)d_in[6];
  const float* bih1 = (const float*)d_in[7];
  const float* bhh1 = (const float*)d_in[8];
  const float* wih2 = (const float*)d_in[9];
  const float* whh2 = (const float*)d_in[10];
  const float* bih2 = (const float*)d_in[11];
  const float* bhh2 = (const float*)d_in[12];
  const float* wout = (const float*)d_in[13];
  const float* bout = (const float*)d_in[14];
  float* out = (float*)d_out;

  rnn3_p8r13<<<dim3(NBAT / 16), dim3(512), 0, stream>>>(
      x, wih0, whh0, bih0, bhh0, wih1, whh1, bih1, bhh1,
      wih2, whh2, bih2, bhh2, wout, bout, out);
}

// Round 14
// 74.898 us; speedup vs baseline: 1.1337x; 1.0937x over previous
//
#include <hip/hip_runtime.h>
#include <hip/hip_fp16.h>

// Fused 3-layer ReLU-RNN + linear head, MI355X (gfx950).
// T=512, B=4096, IN=4, H1=24, H2=48, H3=24, OUT=2.
//
// ROUND 14: round-13 skeleton (8-wave uniform-lag forward pipeline, S=4
// steps/interval, ring-16 LDS, counted LGKM + raw s_barrier, pre-read one
// interval ahead, store-only wS). wB's recurrence rewritten CHAINED-C:
//   b_m = MF(A1c2[m], fc, partial1[m])   // k-chunk2, C = partial1
//   s_m = MF(A1c1[m], fb, C = b_m)       // k-chunk1, C-chained (free fwd)
// MFMA->MFMA C-forwarding is pipelined (m97 GEMM: 16 chained MFMAs at ~5cyc
// effective); the split-accumulator+VALU-add version paid TWO MFMA->VALU
// hazard reads + an add on the loop-carried cycle every step. Now exactly
// ONE MFMA->VALU hazard (the packs) per step; fc packs first (next step's
// earliest MFMAs need it soonest). LDS copies at quad tail (off-chain).

#define TSEQ 512
#define NBAT 4096

typedef float    f32x4 __attribute__((ext_vector_type(4)));
typedef _Float16 f16x8 __attribute__((ext_vector_type(8)));
typedef _Float16 f16x2 __attribute__((ext_vector_type(2)));

union BFrag { f16x8 h; unsigned u[4]; };

__device__ __forceinline__ f32x4 MF(f16x8 a, f16x8 b, f32x4 c) {
  return __builtin_amdgcn_mfma_f32_16x16x32_f16(a, b, c, 0, 0, 0);
}
__device__ __forceinline__ unsigned pkh(float a, float b) {
  union { __half2 h2; unsigned u; } x;
  x.h2 = __floats2half2_rn(a, b);
  return x.u;
}
#if __has_builtin(__builtin_elementwise_max)
// relu applied in f16 after RN pack: relu(rn(x)) == rn(relu(x)) (mod +-0).
__device__ __forceinline__ unsigned pkr(float a, float b) {
  union { __half2 h2; f16x2 f; unsigned u; } x;
  x.h2 = __floats2half2_rn(a, b);
  f16x2 z = {(_Float16)0.f, (_Float16)0.f};
  x.f = __builtin_elementwise_max(x.f, z);
  return x.u;
}
#else
__device__ __forceinline__ unsigned pkr(float a, float b) {
  return pkh(fmaxf(a, 0.f), fmaxf(b, 0.f));
}
#endif

#define SBAR __builtin_amdgcn_sched_barrier(0)
// wait lgkmcnt(n) only (vmcnt=63, expcnt=7)
#define LGKM_WAIT(n) __builtin_amdgcn_s_waitcnt(0xC07F | ((n) << 8))
#define ENDBAR(R)                                                              \
  do {                                                                         \
    SBAR;                                                                      \
    LGKM_WAIT(R);                                                              \
    __builtin_amdgcn_s_barrier();                                              \
    SBAR;                                                                      \
  } while (0)

// ring-16 slot helpers (compile-time for constant PB,U; i0 = 4J so 4*i0 = 0 mod 16)
#define SW16(PB, U)  ((4 * (PB) + (U)) & 15)
#define SR16(PB, U)  ((4 * (PB) + (U) + 12) & 15)
// wC head-item slot (item tau-1 at step tau = 4i-32+U): (4PB+U+15)&15
#define SWAO(PB, U)  ((4 * (PB) + (U) + 15) & 15)
// wS pre-read slot (at interval j for items 4j-37+U): (4PB+U+11)&15
#define SRAO(PB, U)  ((4 * (PB) + (U) + 11) & 15)

struct WP { const float *wih0,*whh0,*wih1,*whh1,*wih2,*whh2,*wout; };

// Concatenated zero-padded weight views:
//  L0 (K=32): k<24 -> W_hh0[m][k], k in [28,32) -> W_ih0[m][k-28]
//  L1 (K=96): k<24 -> W_ih1[m][k], k in [32,80) -> W_hh1[m][k-32]
//  L2 (K=96): k<48 -> W_ih2[m][k], k in [64,88) -> W_hh2[m][k-64]
//  L3 (K=32): k<24 -> W_out[m][k], m<2
__device__ float wcat(int layer, int m, int k, const WP& P) {
  if (layer == 0) {
    if (m < 24) {
      if (k < 24) return P.whh0[m * 24 + k];
      if (k >= 28 && k < 32) return P.wih0[m * 4 + (k - 28)];
    }
    return 0.f;
  } else if (layer == 1) {
    if (m < 48) {
      if (k < 24) return P.wih1[m * 24 + k];
      if (k >= 32 && k < 80) return P.whh1[m * 48 + (k - 32)];
    }
    return 0.f;
  } else if (layer == 2) {
    if (m < 24) {
      if (k < 48) return P.wih2[m * 48 + k];
      if (k >= 64 && k < 88) return P.whh2[m * 24 + (k - 64)];
    }
    return 0.f;
  } else {
    if (m < 2 && k < 24) return P.wout[m * 24 + k];
    return 0.f;
  }
}

__device__ f16x8 afrag(int layer, int mt, int kc, const WP& P) {
  int m  = mt * 16 + (threadIdx.x & 15);
  int kb = kc * 32 + 4 * ((threadIdx.x >> 4) & 3);
  f16x8 r;
#pragma unroll
  for (int j = 0; j < 4; ++j) r[j] = (_Float16)wcat(layer, m, kb + j, P);
#pragma unroll
  for (int j = 0; j < 4; ++j) r[4 + j] = (_Float16)wcat(layer, m, kb + 16 + j, P);
  return r;
}

__device__ f32x4 cfrag(const float* b1, const float* b2, int mt, int nvalid) {
  int qq = (threadIdx.x >> 4) & 3;
  f32x4 r;
#pragma unroll
  for (int i = 0; i < 4; ++i) {
    int m = mt * 16 + 4 * qq + i;
    float v = 0.f;
    if (m < nvalid) { v = b1[m]; if (b2) v += b2[m]; }
    r[i] = v;
  }
  return r;
}

__global__ void __launch_bounds__(512)
rnn3_p8r14(const float* __restrict__ x,
           const float* __restrict__ wih0, const float* __restrict__ whh0,
           const float* __restrict__ bih0, const float* __restrict__ bhh0,
           const float* __restrict__ wih1, const float* __restrict__ whh1,
           const float* __restrict__ bih1, const float* __restrict__ bhh1,
           const float* __restrict__ wih2, const float* __restrict__ whh2,
           const float* __restrict__ bih2, const float* __restrict__ bhh2,
           const float* __restrict__ wout, const float* __restrict__ bout,
           float* __restrict__ out) {
  __shared__ uint4  sH1[16][64];      // h1 packs               16 KB
  __shared__ f32x4  sP1[16][3][64];   // partial1 f32           48 KB
  __shared__ uint4  sH2a[16][64];     // h2[0:32] packs         16 KB
  __shared__ uint2  sH2b[16][64];     // h2[32:48] packs         8 KB
  __shared__ f32x4  sP2a[16][64];     // partial2 mt0 f32       16 KB
  __shared__ f32x4  sP2b[16][64];     // partial2 mt1 f32       16 KB
  __shared__ float2 sAO[16][16];      // head outputs            2 KB

  const int tid  = threadIdx.x;
  const int wid  = tid >> 6;
  const int lane = tid & 63;
  const int c = lane & 15;
  const int q = lane >> 4;
  const int b0 = blockIdx.x * 16;

  WP P{wih0, whh0, wih1, whh1, wih2, whh2, wout};
  const float4* x4 = (const float4*)x;
  float2*       o2 = (float2*)out;

  const int NJ = 35;  // 140 intervals, i = 0..139

  if (wid == 0) {
    // ===== wA: h1 recurrence (2 MFMA/step), items t = 4i+U, i in [0,127] =====
    f16x8 A00 = afrag(0, 0, 0, P), A01 = afrag(0, 1, 0, P);
    f32x4 C00 = cfrag(bih0, bhh0, 0, 24), C01 = cfrag(bih0, bhh0, 1, 24);
    float4 xb[16];
#pragma unroll
    for (int s = 0; s < 16; ++s) xb[s] = x4[(size_t)s * NBAT + b0 + c];
    unsigned fa0 = 0u, fa1 = 0u, fa2 = 0u, fa3 = 0u;  // pure h1 packs

#define A_STEP(PB, U)                                                          \
    {                                                                          \
      float4 xs = xb[SW16(PB, U)];                                             \
      BFrag FAu;                                                               \
      FAu.u[0] = fa0; FAu.u[1] = fa1;                                          \
      FAu.u[2] = (q == 3) ? pkh(xs.x, xs.y) : fa2;                             \
      FAu.u[3] = (q == 3) ? pkh(xs.z, xs.w) : fa3;                             \
      f32x4 a10 = MF(A00, FAu.h, C00);                                         \
      f32x4 a11 = MF(A01, FAu.h, C01);                                         \
      {                                                                        \
        int t = 4 * i + (U);                                                   \
        int tn = (t + 16 < TSEQ) ? t + 16 : TSEQ - 1;                          \
        xb[SW16(PB, U)] = x4[(size_t)tn * NBAT + b0 + c];                      \
      }                                                                        \
      fa0 = pkr(a10[0], a10[1]); fa1 = pkr(a10[2], a10[3]);                    \
      fa2 = pkr(a11[0], a11[1]); fa3 = pkr(a11[2], a11[3]);                    \
      sH1[SW16(PB, U)][lane] = make_uint4(fa0, fa1, fa2, fa3);                 \
    }
#define A_BODY(PB)                                                             \
    {                                                                          \
      int i = i0 + (PB);                                                       \
      if (i <= 127) { A_STEP(PB, 0) A_STEP(PB, 1) A_STEP(PB, 2) A_STEP(PB, 3) }\
      ENDBAR(0);                                                               \
    }
#pragma unroll 1
    for (int J = 0; J < NJ; ++J) {
      int i0 = 4 * J;
      A_BODY(0) A_BODY(1) A_BODY(2) A_BODY(3)
    }
#undef A_BODY
#undef A_STEP

  } else if (wid == 1 || wid == 2) {
    // == wD (mt0,mt1) / wH (mt2): partial1(tau), tau = 4i-8+U, i in [2,129] ==
    const bool isD = (wid == 1);
    f16x8 W0 = afrag(1, isD ? 0 : 2, 0, P);
    f16x8 W1 = isD ? afrag(1, 1, 0, P) : W0;
    f32x4 Cb0 = cfrag(bih1, bhh1, isD ? 0 : 2, 48);
    f32x4 Cb1 = isD ? cfrag(bih1, bhh1, 1, 48) : Cb0;
    uint4 bufA[4], bufB[4];
#pragma unroll
    for (int s = 0; s < 4; ++s) { bufA[s] = make_uint4(0u,0u,0u,0u); bufB[s] = make_uint4(0u,0u,0u,0u); }

#define D_STEP(PB, U, CUR)                                                     \
    {                                                                          \
      BFrag FAu;                                                               \
      FAu.u[0] = CUR[U].x; FAu.u[1] = CUR[U].y;                                \
      FAu.u[2] = CUR[U].z; FAu.u[3] = CUR[U].w;                                \
      f32x4 p0 = MF(W0, FAu.h, Cb0);                                           \
      if (isD) {                                                               \
        f32x4 p1 = MF(W1, FAu.h, Cb1);                                         \
        sP1[SW16(PB, U)][0][lane] = p0;                                        \
        sP1[SW16(PB, U)][1][lane] = p1;                                        \
      } else {                                                                 \
        sP1[SW16(PB, U)][2][lane] = p0;                                        \
      }                                                                        \
    }
#define D_BODY(PB, CUR, NXT)                                                   \
    {                                                                          \
      int i = i0 + (PB);                                                       \
      if (i >= 2 && i <= 129) {                                                \
        D_STEP(PB, 0, CUR) D_STEP(PB, 1, CUR)                                  \
        D_STEP(PB, 2, CUR) D_STEP(PB, 3, CUR)                                  \
      }                                                                        \
      SBAR;                                                                    \
      NXT[0] = sH1[SR16(PB, 0)][lane];                                         \
      NXT[1] = sH1[SR16(PB, 1)][lane];                                         \
      NXT[2] = sH1[SR16(PB, 2)][lane];                                         \
      NXT[3] = sH1[SR16(PB, 3)][lane];                                         \
      ENDBAR(4);                                                               \
    }
#pragma unroll 1
    for (int J = 0; J < NJ; ++J) {
      int i0 = 4 * J;
      D_BODY(0, bufA, bufB) D_BODY(1, bufB, bufA)
      D_BODY(2, bufA, bufB) D_BODY(3, bufB, bufA)
    }
#undef D_BODY
#undef D_STEP

  } else if (wid == 3) {
    // ===== wB: h2 recurrence, items t = 4i-16+U, i in [4,131] =====
    // CHAINED-C: b_m = MF(c2, fc, partial1_m); s_m = MF(c1, fb, b_m).
    // One MFMA->VALU hazard per step (the packs); fc packed first.
    f16x8 A1c1[3], A1c2[3];
#pragma unroll
    for (int mt = 0; mt < 3; ++mt) {
      A1c1[mt] = afrag(1, mt, 1, P);
      A1c2[mt] = afrag(1, mt, 2, P);
    }
    unsigned fb0 = 0u, fb1 = 0u, fb2 = 0u, fb3 = 0u, fc0 = 0u, fc1 = 0u;
    const f32x4 Z4 = {0.f, 0.f, 0.f, 0.f};
    f32x4 pA[4][3], pB[4][3];
#pragma unroll
    for (int s = 0; s < 4; ++s)
#pragma unroll
      for (int m = 0; m < 3; ++m) { pA[s][m] = Z4; pB[s][m] = Z4; }

#define B_STEPC(PB, U, CUR, H2A, H2B)                                          \
    {                                                                          \
      BFrag Ff, Gf;                                                            \
      Ff.u[0] = fb0; Ff.u[1] = fb1; Ff.u[2] = fb2; Ff.u[3] = fb3;              \
      Gf.u[0] = fc0; Gf.u[1] = fc1; Gf.u[2] = 0u; Gf.u[3] = 0u;                \
      f32x4 b0 = MF(A1c2[0], Gf.h, CUR[U][0]);                                 \
      f32x4 b1 = MF(A1c2[1], Gf.h, CUR[U][1]);                                 \
      f32x4 b2 = MF(A1c2[2], Gf.h, CUR[U][2]);                                 \
      f32x4 s2v = MF(A1c1[2], Ff.h, b2);   /* feeds fc: issue early */         \
      f32x4 s0v = MF(A1c1[0], Ff.h, b0);                                       \
      f32x4 s1v = MF(A1c1[1], Ff.h, b1);                                       \
      fc0 = pkr(s2v[0], s2v[1]); fc1 = pkr(s2v[2], s2v[3]);                    \
      fb0 = pkr(s0v[0], s0v[1]); fb1 = pkr(s0v[2], s0v[3]);                    \
      fb2 = pkr(s1v[0], s1v[1]); fb3 = pkr(s1v[2], s1v[3]);                    \
      H2A[U] = make_uint4(fb0, fb1, fb2, fb3);                                 \
      H2B[U] = make_uint2(fc0, fc1);                                           \
    }
#define B_BODY(PB, CUR, NXT)                                                   \
    {                                                                          \
      int i = i0 + (PB);                                                       \
      uint4 h2aq[4]; uint2 h2bq[4];                                            \
      if (i >= 4 && i <= 131) {                                                \
        B_STEPC(PB, 0, CUR, h2aq, h2bq)                                        \
        B_STEPC(PB, 1, CUR, h2aq, h2bq)                                        \
        B_STEPC(PB, 2, CUR, h2aq, h2bq)                                        \
        B_STEPC(PB, 3, CUR, h2aq, h2bq)                                        \
        /* deferred LDS copies (off the loop-carried chain) */                 \
        sH2a[SW16(PB, 0)][lane] = h2aq[0];                                     \
        sH2b[SW16(PB, 0)][lane] = h2bq[0];                                     \
        sH2a[SW16(PB, 1)][lane] = h2aq[1];                                     \
        sH2b[SW16(PB, 1)][lane] = h2bq[1];                                     \
        sH2a[SW16(PB, 2)][lane] = h2aq[2];                                     \
        sH2b[SW16(PB, 2)][lane] = h2bq[2];                                     \
        sH2a[SW16(PB, 3)][lane] = h2aq[3];                                     \
        sH2b[SW16(PB, 3)][lane] = h2bq[3];                                     \
      }                                                                        \
      SBAR;                                                                    \
      NXT[0][0] = sP1[SR16(PB, 0)][0][lane];                                   \
      NXT[0][1] = sP1[SR16(PB, 0)][1][lane];                                   \
      NXT[0][2] = sP1[SR16(PB, 0)][2][lane];                                   \
      NXT[1][0] = sP1[SR16(PB, 1)][0][lane];                                   \
      NXT[1][1] = sP1[SR16(PB, 1)][1][lane];                                   \
      NXT[1][2] = sP1[SR16(PB, 1)][2][lane];                                   \
      NXT[2][0] = sP1[SR16(PB, 2)][0][lane];                                   \
      NXT[2][1] = sP1[SR16(PB, 2)][1][lane];                                   \
      NXT[2][2] = sP1[SR16(PB, 2)][2][lane];                                   \
      NXT[3][0] = sP1[SR16(PB, 3)][0][lane];                                   \
      NXT[3][1] = sP1[SR16(PB, 3)][1][lane];                                   \
      NXT[3][2] = sP1[SR16(PB, 3)][2][lane];                                   \
      ENDBAR(12);                                                              \
    }
#pragma unroll 1
    for (int J = 0; J < NJ; ++J) {
      int i0 = 4 * J;
      B_BODY(0, pA, pB) B_BODY(1, pB, pA) B_BODY(2, pA, pB) B_BODY(3, pB, pA)
    }
#undef B_BODY
#undef B_STEPC

  } else if (wid == 4 || wid == 5) {
    // == wE (mt0) / wF (mt1): partial2(tau), tau = 4i-24+U, i in [6,133] ==
    const int mt = (wid == 4) ? 0 : 1;
    f16x8 W0 = afrag(2, mt, 0, P), W1 = afrag(2, mt, 1, P);
    f32x4 Cb = cfrag(bih2, bhh2, mt, 24);
    uint4 haA[4], haB[4];
    uint2 hbA[4], hbB[4];
#pragma unroll
    for (int s = 0; s < 4; ++s) {
      haA[s] = make_uint4(0u,0u,0u,0u); haB[s] = make_uint4(0u,0u,0u,0u);
      hbA[s] = make_uint2(0u,0u);       hbB[s] = make_uint2(0u,0u);
    }

#define E_STEP(PB, U, CA, CB)                                                  \
    {                                                                          \
      BFrag FBu, FCu;                                                          \
      FBu.u[0] = CA[U].x; FBu.u[1] = CA[U].y;                                  \
      FBu.u[2] = CA[U].z; FBu.u[3] = CA[U].w;                                  \
      FCu.u[0] = CB[U].x; FCu.u[1] = CB[U].y;                                  \
      FCu.u[2] = 0u; FCu.u[3] = 0u;                                            \
      f32x4 p = MF(W0, FBu.h, Cb);                                             \
      p = MF(W1, FCu.h, p);                                                    \
      if (mt == 0) sP2a[SW16(PB, U)][lane] = p;                                \
      else         sP2b[SW16(PB, U)][lane] = p;                                \
    }
#define E_BODY(PB, CA, CB, NA, NB)                                             \
    {                                                                          \
      int i = i0 + (PB);                                                       \
      if (i >= 6 && i <= 133) {                                                \
        E_STEP(PB, 0, CA, CB) E_STEP(PB, 1, CA, CB)                            \
        E_STEP(PB, 2, CA, CB) E_STEP(PB, 3, CA, CB)                            \
      }                                                                        \
      SBAR;                                                                    \
      NA[0] = sH2a[SR16(PB, 0)][lane];                                         \
      NA[1] = sH2a[SR16(PB, 1)][lane];                                         \
      NA[2] = sH2a[SR16(PB, 2)][lane];                                         \
      NA[3] = sH2a[SR16(PB, 3)][lane];                                         \
      NB[0] = sH2b[SR16(PB, 0)][lane];                                         \
      NB[1] = sH2b[SR16(PB, 1)][lane];                                         \
      NB[2] = sH2b[SR16(PB, 2)][lane];                                         \
      NB[3] = sH2b[SR16(PB, 3)][lane];                                         \
      ENDBAR(8);                                                               \
    }
#pragma unroll 1
    for (int J = 0; J < NJ; ++J) {
      int i0 = 4 * J;
      E_BODY(0, haA, hbA, haB, hbB) E_BODY(1, haB, hbB, haA, hbA)
      E_BODY(2, haA, hbA, haB, hbB) E_BODY(3, haB, hbB, haA, hbA)
    }
#undef E_BODY
#undef E_STEP

  } else if (wid == 6) {
    // ===== wC: h3 recurrence + head, steps tau = 4i-32+U, i in [8,136] =====
    f16x8 A2c2m0 = afrag(2, 0, 2, P), A2c2m1 = afrag(2, 1, 2, P);
    f16x8 A3 = afrag(3, 0, 0, P);
    f32x4 C3 = cfrag(bout, nullptr, 0, 2);
    unsigned fd0 = 0u, fd1 = 0u, fd2 = 0u, fd3 = 0u;
    const f32x4 Z4 = {0.f, 0.f, 0.f, 0.f};
    f32x4 paA[4], paB[4], pbA[4], pbB[4];
#pragma unroll
    for (int s = 0; s < 4; ++s) { paA[s] = Z4; paB[s] = Z4; pbA[s] = Z4; pbB[s] = Z4; }

#define C_STEP(PB, U, CA, CB)                                                  \
    {                                                                          \
      BFrag FDu;                                                               \
      FDu.u[0] = fd0; FDu.u[1] = fd1; FDu.u[2] = fd2; FDu.u[3] = fd3;          \
      f32x4 a30 = MF(A2c2m0, FDu.h, CA[U]);                                    \
      f32x4 a31 = MF(A2c2m1, FDu.h, CB[U]);                                    \
      f32x4 ao = MF(A3, FDu.h, C3);          /* head(tau-1) */                 \
      int th = 4 * i - 33 + (U);                                               \
      if (th >= 0 && th < TSEQ && q == 0)                                      \
        sAO[SWAO(PB, U)][c] = make_float2(ao[0], ao[1]);                       \
      fd0 = pkr(a30[0], a30[1]); fd1 = pkr(a30[2], a30[3]);                    \
      fd2 = pkr(a31[0], a31[1]); fd3 = pkr(a31[2], a31[3]);                    \
    }
#define C_BODY(PB, CA, CB, NA, NB)                                             \
    {                                                                          \
      int i = i0 + (PB);                                                       \
      if (i >= 8 && i <= 136) {                                                \
        C_STEP(PB, 0, CA, CB) C_STEP(PB, 1, CA, CB)                            \
        C_STEP(PB, 2, CA, CB) C_STEP(PB, 3, CA, CB)                            \
      }                                                                        \
      SBAR;                                                                    \
      NA[0] = sP2a[SR16(PB, 0)][lane];                                         \
      NA[1] = sP2a[SR16(PB, 1)][lane];                                         \
      NA[2] = sP2a[SR16(PB, 2)][lane];                                         \
      NA[3] = sP2a[SR16(PB, 3)][lane];                                         \
      NB[0] = sP2b[SR16(PB, 0)][lane];                                         \
      NB[1] = sP2b[SR16(PB, 1)][lane];                                         \
      NB[2] = sP2b[SR16(PB, 2)][lane];                                         \
      NB[3] = sP2b[SR16(PB, 3)][lane];                                         \
      ENDBAR(8);                                                               \
    }
#pragma unroll 1
    for (int J = 0; J < NJ; ++J) {
      int i0 = 4 * J;
      C_BODY(0, paA, pbA, paB, pbB) C_BODY(1, paB, pbB, paA, pbA)
      C_BODY(2, paA, pbA, paB, pbB) C_BODY(3, paB, pbB, paA, pbA)
    }
#undef C_BODY
#undef C_STEP

  } else {
    // ===== wS: store-only (0 MFMA), items t = 4j-41+U, j in [10,138] =====
    float2 aoA[4], aoB[4];
#pragma unroll
    for (int s = 0; s < 4; ++s) { aoA[s] = make_float2(0.f, 0.f); aoB[s] = make_float2(0.f, 0.f); }

#define S_STEP(PB, U, CUR)                                                     \
    {                                                                          \
      int t = 4 * i - 41 + (U);                                                \
      if (t >= 0 && t < TSEQ && q == 0)                                        \
        o2[(size_t)t * NBAT + b0 + c] = CUR[U];                                \
    }
#define S_BODY(PB, CUR, NXT)                                                   \
    {                                                                          \
      int i = i0 + (PB);                                                       \
      if (i >= 10 && i <= 138) {                                               \
        S_STEP(PB, 0, CUR) S_STEP(PB, 1, CUR)                                  \
        S_STEP(PB, 2, CUR) S_STEP(PB, 3, CUR)                                  \
      }                                                                        \
      SBAR;                                                                    \
      NXT[0] = sAO[SRAO(PB, 0)][c];                                            \
      NXT[1] = sAO[SRAO(PB, 1)][c];                                            \
      NXT[2] = sAO[SRAO(PB, 2)][c];                                            \
      NXT[3] = sAO[SRAO(PB, 3)][c];                                            \
      ENDBAR(4);                                                               \
    }
#pragma unroll 1
    for (int J = 0; J < NJ; ++J) {
      int i0 = 4 * J;
      S_BODY(0, aoA, aoB) S_BODY(1, aoB, aoA)
      S_BODY(2, aoA, aoB) S_BODY(3, aoB, aoA)
    }
#undef S_BODY
#undef S_STEP
  }
}

extern "C" void kernel_launch(void* const* d_in, const int* in_sizes, int n_in,
                              void* d_out, int out_size, void* d_ws, size_t ws_size,
                              hipStream_t stream) {
  const float* x    = (const float*)d_in[0];
  const float* wih0 = (const float*)d_in[1];
  const float* whh0 = (const float*)d_in[2];
  const float* bih0 = (const float*)d_in[3];
  const float* bhh0 = (const float*)d_in[4];
  const float* wih1 = (const float*)d_in[5];
  const float* whh1 = (const float*)d_in[6];
  const float* bih1 = (const float*)d_in[7];
  const float* bhh1 = (const float*)d_in[8];
  const float* wih2 = (const float*)d_in[9];
  const float* whh2 = (const float*)d_in[10];
  const float* bih2 = (const float*)d_in[11];
  const float* bhh2 = (const float*)d_in[12];
  const float* wout = (const float*)d_in[13];
  const float* bout = (const float*)d_in[14];
  float* out = (float*)d_out;

  rnn3_p8r14<<<dim3(NBAT / 16), dim3(512), 0, stream>>>(
      x, wih0, whh0, bih0, bhh0, wih1, whh1, bih1, bhh1,
      wih2, whh2, bih2, bhh2, wout, bout, out);
}

// Round 15
// 73.214 us; speedup vs baseline: 1.1598x; 1.0230x over previous
//
#include <hip/hip_runtime.h>
#include <hip/hip_fp16.h>

// Fused 3-layer ReLU-RNN + linear head, MI355X (gfx950).
// T=512, B=4096, IN=4, H1=24, H2=48, H3=24, OUT=2.
//
// ROUND 15: round-14 skeleton (8-wave uniform-lag forward pipeline, S=4
// steps/interval, ring-16 LDS, chained-C wB, store-only wS) with two
// latency fixes:
//  (1) All consumer LDS pre-reads moved from the END of the body (where
//      their ~120-cyc latency was exposed at the next interval's first
//      MFMA — the critical wave arrives at the barrier last, so barrier
//      wait ~0) to the TOP of the body: same slots (data drained 1+
//      intervals ago), now ~1200 cyc to complete before use. ENDBAR
//      counts drop to 0 (only tail writes drain at the barrier).
//  (2) wB per-step issue order: b2 -> s2v -> b0 -> b1 -> s0v -> s1v, so
//      the fc-producing chain starts at issue slot 0 and its latency
//      hides under the remaining 4 MFMAs; fc packs first.
// Dataflow and arithmetic bit-identical to round 14.

#define TSEQ 512
#define NBAT 4096

typedef float    f32x4 __attribute__((ext_vector_type(4)));
typedef _Float16 f16x8 __attribute__((ext_vector_type(8)));
typedef _Float16 f16x2 __attribute__((ext_vector_type(2)));

union BFrag { f16x8 h; unsigned u[4]; };

__device__ __forceinline__ f32x4 MF(f16x8 a, f16x8 b, f32x4 c) {
  return __builtin_amdgcn_mfma_f32_16x16x32_f16(a, b, c, 0, 0, 0);
}
__device__ __forceinline__ unsigned pkh(float a, float b) {
  union { __half2 h2; unsigned u; } x;
  x.h2 = __floats2half2_rn(a, b);
  return x.u;
}
#if __has_builtin(__builtin_elementwise_max)
// relu applied in f16 after RN pack: relu(rn(x)) == rn(relu(x)) (mod +-0).
__device__ __forceinline__ unsigned pkr(float a, float b) {
  union { __half2 h2; f16x2 f; unsigned u; } x;
  x.h2 = __floats2half2_rn(a, b);
  f16x2 z = {(_Float16)0.f, (_Float16)0.f};
  x.f = __builtin_elementwise_max(x.f, z);
  return x.u;
}
#else
__device__ __forceinline__ unsigned pkr(float a, float b) {
  return pkh(fmaxf(a, 0.f), fmaxf(b, 0.f));
}
#endif

#define SBAR __builtin_amdgcn_sched_barrier(0)
// wait lgkmcnt(n) only (vmcnt=63, expcnt=7)
#define LGKM_WAIT(n) __builtin_amdgcn_s_waitcnt(0xC07F | ((n) << 8))
#define ENDBAR0                                                                \
  do {                                                                         \
    SBAR;                                                                      \
    LGKM_WAIT(0);                                                              \
    __builtin_amdgcn_s_barrier();                                              \
    SBAR;                                                                      \
  } while (0)

// ring-16 slot helpers (compile-time for constant PB,U; i0 = 4J so 4*i0 = 0 mod 16)
#define SW16(PB, U)  ((4 * (PB) + (U)) & 15)
#define SR16(PB, U)  ((4 * (PB) + (U) + 12) & 15)
// wC head-item slot (item tau-1 at step tau = 4i-32+U): (4PB+U+15)&15
#define SWAO(PB, U)  ((4 * (PB) + (U) + 15) & 15)
// wS pre-read slot (at interval j for items 4j-37+U): (4PB+U+11)&15
#define SRAO(PB, U)  ((4 * (PB) + (U) + 11) & 15)

struct WP { const float *wih0,*whh0,*wih1,*whh1,*wih2,*whh2,*wout; };

// Concatenated zero-padded weight views:
//  L0 (K=32): k<24 -> W_hh0[m][k], k in [28,32) -> W_ih0[m][k-28]
//  L1 (K=96): k<24 -> W_ih1[m][k], k in [32,80) -> W_hh1[m][k-32]
//  L2 (K=96): k<48 -> W_ih2[m][k], k in [64,88) -> W_hh2[m][k-64]
//  L3 (K=32): k<24 -> W_out[m][k], m<2
__device__ float wcat(int layer, int m, int k, const WP& P) {
  if (layer == 0) {
    if (m < 24) {
      if (k < 24) return P.whh0[m * 24 + k];
      if (k >= 28 && k < 32) return P.wih0[m * 4 + (k - 28)];
    }
    return 0.f;
  } else if (layer == 1) {
    if (m < 48) {
      if (k < 24) return P.wih1[m * 24 + k];
      if (k >= 32 && k < 80) return P.whh1[m * 48 + (k - 32)];
    }
    return 0.f;
  } else if (layer == 2) {
    if (m < 24) {
      if (k < 48) return P.wih2[m * 48 + k];
      if (k >= 64 && k < 88) return P.whh2[m * 24 + (k - 64)];
    }
    return 0.f;
  } else {
    if (m < 2 && k < 24) return P.wout[m * 24 + k];
    return 0.f;
  }
}

__device__ f16x8 afrag(int layer, int mt, int kc, const WP& P) {
  int m  = mt * 16 + (threadIdx.x & 15);
  int kb = kc * 32 + 4 * ((threadIdx.x >> 4) & 3);
  f16x8 r;
#pragma unroll
  for (int j = 0; j < 4; ++j) r[j] = (_Float16)wcat(layer, m, kb + j, P);
#pragma unroll
  for (int j = 0; j < 4; ++j) r[4 + j] = (_Float16)wcat(layer, m, kb + 16 + j, P);
  return r;
}

__device__ f32x4 cfrag(const float* b1, const float* b2, int mt, int nvalid) {
  int qq = (threadIdx.x >> 4) & 3;
  f32x4 r;
#pragma unroll
  for (int i = 0; i < 4; ++i) {
    int m = mt * 16 + 4 * qq + i;
    float v = 0.f;
    if (m < nvalid) { v = b1[m]; if (b2) v += b2[m]; }
    r[i] = v;
  }
  return r;
}

__global__ void __launch_bounds__(512)
rnn3_p8r15(const float* __restrict__ x,
           const float* __restrict__ wih0, const float* __restrict__ whh0,
           const float* __restrict__ bih0, const float* __restrict__ bhh0,
           const float* __restrict__ wih1, const float* __restrict__ whh1,
           const float* __restrict__ bih1, const float* __restrict__ bhh1,
           const float* __restrict__ wih2, const float* __restrict__ whh2,
           const float* __restrict__ bih2, const float* __restrict__ bhh2,
           const float* __restrict__ wout, const float* __restrict__ bout,
           float* __restrict__ out) {
  __shared__ uint4  sH1[16][64];      // h1 packs               16 KB
  __shared__ f32x4  sP1[16][3][64];   // partial1 f32           48 KB
  __shared__ uint4  sH2a[16][64];     // h2[0:32] packs         16 KB
  __shared__ uint2  sH2b[16][64];     // h2[32:48] packs         8 KB
  __shared__ f32x4  sP2a[16][64];     // partial2 mt0 f32       16 KB
  __shared__ f32x4  sP2b[16][64];     // partial2 mt1 f32       16 KB
  __shared__ float2 sAO[16][16];      // head outputs            2 KB

  const int tid  = threadIdx.x;
  const int wid  = tid >> 6;
  const int lane = tid & 63;
  const int c = lane & 15;
  const int q = lane >> 4;
  const int b0 = blockIdx.x * 16;

  WP P{wih0, whh0, wih1, whh1, wih2, whh2, wout};
  const float4* x4 = (const float4*)x;
  float2*       o2 = (float2*)out;

  const int NJ = 35;  // 140 intervals, i = 0..139

  if (wid == 0) {
    // ===== wA: h1 recurrence (2 MFMA/step), items t = 4i+U, i in [0,127] =====
    f16x8 A00 = afrag(0, 0, 0, P), A01 = afrag(0, 1, 0, P);
    f32x4 C00 = cfrag(bih0, bhh0, 0, 24), C01 = cfrag(bih0, bhh0, 1, 24);
    float4 xb[16];
#pragma unroll
    for (int s = 0; s < 16; ++s) xb[s] = x4[(size_t)s * NBAT + b0 + c];
    unsigned fa0 = 0u, fa1 = 0u, fa2 = 0u, fa3 = 0u;  // pure h1 packs

#define A_STEP(PB, U)                                                          \
    {                                                                          \
      float4 xs = xb[SW16(PB, U)];                                             \
      BFrag FAu;                                                               \
      FAu.u[0] = fa0; FAu.u[1] = fa1;                                          \
      FAu.u[2] = (q == 3) ? pkh(xs.x, xs.y) : fa2;                             \
      FAu.u[3] = (q == 3) ? pkh(xs.z, xs.w) : fa3;                             \
      f32x4 a10 = MF(A00, FAu.h, C00);                                         \
      f32x4 a11 = MF(A01, FAu.h, C01);                                         \
      {                                                                        \
        int t = 4 * i + (U);                                                   \
        int tn = (t + 16 < TSEQ) ? t + 16 : TSEQ - 1;                          \
        xb[SW16(PB, U)] = x4[(size_t)tn * NBAT + b0 + c];                      \
      }                                                                        \
      fa0 = pkr(a10[0], a10[1]); fa1 = pkr(a10[2], a10[3]);                    \
      fa2 = pkr(a11[0], a11[1]); fa3 = pkr(a11[2], a11[3]);                    \
      sH1[SW16(PB, U)][lane] = make_uint4(fa0, fa1, fa2, fa3);                 \
    }
#define A_BODY(PB)                                                             \
    {                                                                          \
      int i = i0 + (PB);                                                       \
      if (i <= 127) { A_STEP(PB, 0) A_STEP(PB, 1) A_STEP(PB, 2) A_STEP(PB, 3) }\
      ENDBAR0;                                                                 \
    }
#pragma unroll 1
    for (int J = 0; J < NJ; ++J) {
      int i0 = 4 * J;
      A_BODY(0) A_BODY(1) A_BODY(2) A_BODY(3)
    }
#undef A_BODY
#undef A_STEP

  } else if (wid == 1 || wid == 2) {
    // == wD (mt0,mt1) / wH (mt2): partial1(tau), tau = 4i-8+U, i in [2,129] ==
    const bool isD = (wid == 1);
    f16x8 W0 = afrag(1, isD ? 0 : 2, 0, P);
    f16x8 W1 = isD ? afrag(1, 1, 0, P) : W0;
    f32x4 Cb0 = cfrag(bih1, bhh1, isD ? 0 : 2, 48);
    f32x4 Cb1 = isD ? cfrag(bih1, bhh1, 1, 48) : Cb0;
    uint4 bufA[4], bufB[4];
#pragma unroll
    for (int s = 0; s < 4; ++s) { bufA[s] = make_uint4(0u,0u,0u,0u); bufB[s] = make_uint4(0u,0u,0u,0u); }

#define D_STEP(PB, U, CUR)                                                     \
    {                                                                          \
      BFrag FAu;                                                               \
      FAu.u[0] = CUR[U].x; FAu.u[1] = CUR[U].y;                                \
      FAu.u[2] = CUR[U].z; FAu.u[3] = CUR[U].w;                                \
      f32x4 p0 = MF(W0, FAu.h, Cb0);                                           \
      if (isD) {                                                               \
        f32x4 p1 = MF(W1, FAu.h, Cb1);                                         \
        sP1[SW16(PB, U)][0][lane] = p0;                                        \
        sP1[SW16(PB, U)][1][lane] = p1;                                        \
      } else {                                                                 \
        sP1[SW16(PB, U)][2][lane] = p0;                                        \
      }                                                                        \
    }
#define D_BODY(PB, CUR, NXT)                                                   \
    {                                                                          \
      int i = i0 + (PB);                                                       \
      NXT[0] = sH1[SR16(PB, 0)][lane];   /* top pre-reads (for i+1) */         \
      NXT[1] = sH1[SR16(PB, 1)][lane];                                         \
      NXT[2] = sH1[SR16(PB, 2)][lane];                                         \
      NXT[3] = sH1[SR16(PB, 3)][lane];                                         \
      SBAR;                                                                    \
      if (i >= 2 && i <= 129) {                                                \
        D_STEP(PB, 0, CUR) D_STEP(PB, 1, CUR)                                  \
        D_STEP(PB, 2, CUR) D_STEP(PB, 3, CUR)                                  \
      }                                                                        \
      ENDBAR0;                                                                 \
    }
#pragma unroll 1
    for (int J = 0; J < NJ; ++J) {
      int i0 = 4 * J;
      D_BODY(0, bufA, bufB) D_BODY(1, bufB, bufA)
      D_BODY(2, bufA, bufB) D_BODY(3, bufB, bufA)
    }
#undef D_BODY
#undef D_STEP

  } else if (wid == 3) {
    // ===== wB: h2 recurrence, items t = 4i-16+U, i in [4,131] =====
    // CHAINED-C, fc-chain first: b2 -> s2v -> b0 -> b1 -> s0v -> s1v.
    f16x8 A1c1[3], A1c2[3];
#pragma unroll
    for (int mt = 0; mt < 3; ++mt) {
      A1c1[mt] = afrag(1, mt, 1, P);
      A1c2[mt] = afrag(1, mt, 2, P);
    }
    unsigned fb0 = 0u, fb1 = 0u, fb2 = 0u, fb3 = 0u, fc0 = 0u, fc1 = 0u;
    const f32x4 Z4 = {0.f, 0.f, 0.f, 0.f};
    f32x4 pA[4][3], pB[4][3];
#pragma unroll
    for (int s = 0; s < 4; ++s)
#pragma unroll
      for (int m = 0; m < 3; ++m) { pA[s][m] = Z4; pB[s][m] = Z4; }

#define B_STEPC(PB, U, CUR, H2A, H2B)                                          \
    {                                                                          \
      BFrag Ff, Gf;                                                            \
      Ff.u[0] = fb0; Ff.u[1] = fb1; Ff.u[2] = fb2; Ff.u[3] = fb3;              \
      Gf.u[0] = fc0; Gf.u[1] = fc1; Gf.u[2] = 0u; Gf.u[3] = 0u;                \
      f32x4 b2 = MF(A1c2[2], Gf.h, CUR[U][2]);   /* fc-chain head */           \
      f32x4 s2v = MF(A1c1[2], Ff.h, b2);         /* C-chained      */          \
      f32x4 b0 = MF(A1c2[0], Gf.h, CUR[U][0]);                                 \
      f32x4 b1 = MF(A1c2[1], Gf.h, CUR[U][1]);                                 \
      f32x4 s0v = MF(A1c1[0], Ff.h, b0);                                       \
      f32x4 s1v = MF(A1c1[1], Ff.h, b1);                                       \
      fc0 = pkr(s2v[0], s2v[1]); fc1 = pkr(s2v[2], s2v[3]);                    \
      fb0 = pkr(s0v[0], s0v[1]); fb1 = pkr(s0v[2], s0v[3]);                    \
      fb2 = pkr(s1v[0], s1v[1]); fb3 = pkr(s1v[2], s1v[3]);                    \
      H2A[U] = make_uint4(fb0, fb1, fb2, fb3);                                 \
      H2B[U] = make_uint2(fc0, fc1);                                           \
    }
#define B_BODY(PB, CUR, NXT)                                                   \
    {                                                                          \
      int i = i0 + (PB);                                                       \
      NXT[0][0] = sP1[SR16(PB, 0)][0][lane];  /* top pre-reads (for i+1) */    \
      NXT[0][1] = sP1[SR16(PB, 0)][1][lane];                                   \
      NXT[0][2] = sP1[SR16(PB, 0)][2][lane];                                   \
      NXT[1][0] = sP1[SR16(PB, 1)][0][lane];                                   \
      NXT[1][1] = sP1[SR16(PB, 1)][1][lane];                                   \
      NXT[1][2] = sP1[SR16(PB, 1)][2][lane];                                   \
      NXT[2][0] = sP1[SR16(PB, 2)][0][lane];                                   \
      NXT[2][1] = sP1[SR16(PB, 2)][1][lane];                                   \
      NXT[2][2] = sP1[SR16(PB, 2)][2][lane];                                   \
      NXT[3][0] = sP1[SR16(PB, 3)][0][lane];                                   \
      NXT[3][1] = sP1[SR16(PB, 3)][1][lane];                                   \
      NXT[3][2] = sP1[SR16(PB, 3)][2][lane];                                   \
      SBAR;                                                                    \
      uint4 h2aq[4]; uint2 h2bq[4];                                            \
      if (i >= 4 && i <= 131) {                                                \
        B_STEPC(PB, 0, CUR, h2aq, h2bq)                                        \
        B_STEPC(PB, 1, CUR, h2aq, h2bq)                                        \
        B_STEPC(PB, 2, CUR, h2aq, h2bq)                                        \
        B_STEPC(PB, 3, CUR, h2aq, h2bq)                                        \
        sH2a[SW16(PB, 0)][lane] = h2aq[0];                                     \
        sH2b[SW16(PB, 0)][lane] = h2bq[0];                                     \
        sH2a[SW16(PB, 1)][lane] = h2aq[1];                                     \
        sH2b[SW16(PB, 1)][lane] = h2bq[1];                                     \
        sH2a[SW16(PB, 2)][lane] = h2aq[2];                                     \
        sH2b[SW16(PB, 2)][lane] = h2bq[2];                                     \
        sH2a[SW16(PB, 3)][lane] = h2aq[3];                                     \
        sH2b[SW16(PB, 3)][lane] = h2bq[3];                                     \
      }                                                                        \
      ENDBAR0;                                                                 \
    }
#pragma unroll 1
    for (int J = 0; J < NJ; ++J) {
      int i0 = 4 * J;
      B_BODY(0, pA, pB) B_BODY(1, pB, pA) B_BODY(2, pA, pB) B_BODY(3, pB, pA)
    }
#undef B_BODY
#undef B_STEPC

  } else if (wid == 4 || wid == 5) {
    // == wE (mt0) / wF (mt1): partial2(tau), tau = 4i-24+U, i in [6,133] ==
    const int mt = (wid == 4) ? 0 : 1;
    f16x8 W0 = afrag(2, mt, 0, P), W1 = afrag(2, mt, 1, P);
    f32x4 Cb = cfrag(bih2, bhh2, mt, 24);
    uint4 haA[4], haB[4];
    uint2 hbA[4], hbB[4];
#pragma unroll
    for (int s = 0; s < 4; ++s) {
      haA[s] = make_uint4(0u,0u,0u,0u); haB[s] = make_uint4(0u,0u,0u,0u);
      hbA[s] = make_uint2(0u,0u);       hbB[s] = make_uint2(0u,0u);
    }

#define E_STEP(PB, U, CA, CB)                                                  \
    {                                                                          \
      BFrag FBu, FCu;                                                          \
      FBu.u[0] = CA[U].x; FBu.u[1] = CA[U].y;                                  \
      FBu.u[2] = CA[U].z; FBu.u[3] = CA[U].w;                                  \
      FCu.u[0] = CB[U].x; FCu.u[1] = CB[U].y;                                  \
      FCu.u[2] = 0u; FCu.u[3] = 0u;                                            \
      f32x4 p = MF(W0, FBu.h, Cb);                                             \
      p = MF(W1, FCu.h, p);                                                    \
      if (mt == 0) sP2a[SW16(PB, U)][lane] = p;                                \
      else         sP2b[SW16(PB, U)][lane] = p;                                \
    }
#define E_BODY(PB, CA, CB, NA, NB)                                             \
    {                                                                          \
      int i = i0 + (PB);                                                       \
      NA[0] = sH2a[SR16(PB, 0)][lane];   /* top pre-reads (for i+1) */         \
      NA[1] = sH2a[SR16(PB, 1)][lane];                                         \
      NA[2] = sH2a[SR16(PB, 2)][lane];                                         \
      NA[3] = sH2a[SR16(PB, 3)][lane];                                         \
      NB[0] = sH2b[SR16(PB, 0)][lane];                                         \
      NB[1] = sH2b[SR16(PB, 1)][lane];                                         \
      NB[2] = sH2b[SR16(PB, 2)][lane];                                         \
      NB[3] = sH2b[SR16(PB, 3)][lane];                                         \
      SBAR;                                                                    \
      if (i >= 6 && i <= 133) {                                                \
        E_STEP(PB, 0, CA, CB) E_STEP(PB, 1, CA, CB)                            \
        E_STEP(PB, 2, CA, CB) E_STEP(PB, 3, CA, CB)                            \
      }                                                                        \
      ENDBAR0;                                                                 \
    }
#pragma unroll 1
    for (int J = 0; J < NJ; ++J) {
      int i0 = 4 * J;
      E_BODY(0, haA, hbA, haB, hbB) E_BODY(1, haB, hbB, haA, hbA)
      E_BODY(2, haA, hbA, haB, hbB) E_BODY(3, haB, hbB, haA, hbA)
    }
#undef E_BODY
#undef E_STEP

  } else if (wid == 6) {
    // ===== wC: h3 recurrence + head, steps tau = 4i-32+U, i in [8,136] =====
    f16x8 A2c2m0 = afrag(2, 0, 2, P), A2c2m1 = afrag(2, 1, 2, P);
    f16x8 A3 = afrag(3, 0, 0, P);
    f32x4 C3 = cfrag(bout, nullptr, 0, 2);
    unsigned fd0 = 0u, fd1 = 0u, fd2 = 0u, fd3 = 0u;
    const f32x4 Z4 = {0.f, 0.f, 0.f, 0.f};
    f32x4 paA[4], paB[4], pbA[4], pbB[4];
#pragma unroll
    for (int s = 0; s < 4; ++s) { paA[s] = Z4; paB[s] = Z4; pbA[s] = Z4; pbB[s] = Z4; }

#define C_STEP(PB, U, CA, CB)                                                  \
    {                                                                          \
      BFrag FDu;                                                               \
      FDu.u[0] = fd0; FDu.u[1] = fd1; FDu.u[2] = fd2; FDu.u[3] = fd3;          \
      f32x4 a30 = MF(A2c2m0, FDu.h, CA[U]);                                    \
      f32x4 a31 = MF(A2c2m1, FDu.h, CB[U]);                                    \
      f32x4 ao = MF(A3, FDu.h, C3);          /* head(tau-1) */                 \
      int th = 4 * i - 33 + (U);                                               \
      if (th >= 0 && th < TSEQ && q == 0)                                      \
        sAO[SWAO(PB, U)][c] = make_float2(ao[0], ao[1]);                       \
      fd0 = pkr(a30[0], a30[1]); fd1 = pkr(a30[2], a30[3]);                    \
      fd2 = pkr(a31[0], a31[1]); fd3 = pkr(a31[2], a31[3]);                    \
    }
#define C_BODY(PB, CA, CB, NA, NB)                                             \
    {                                                                          \
      int i = i0 + (PB);                                                       \
      NA[0] = sP2a[SR16(PB, 0)][lane];   /* top pre-reads (for i+1) */         \
      NA[1] = sP2a[SR16(PB, 1)][lane];                                         \
      NA[2] = sP2a[SR16(PB, 2)][lane];                                         \
      NA[3] = sP2a[SR16(PB, 3)][lane];                                         \
      NB[0] = sP2b[SR16(PB, 0)][lane];                                         \
      NB[1] = sP2b[SR16(PB, 1)][lane];                                         \
      NB[2] = sP2b[SR16(PB, 2)][lane];                                         \
      NB[3] = sP2b[SR16(PB, 3)][lane];                                         \
      SBAR;                                                                    \
      if (i >= 8 && i <= 136) {                                                \
        C_STEP(PB, 0, CA, CB) C_STEP(PB, 1, CA, CB)                            \
        C_STEP(PB, 2, CA, CB) C_STEP(PB, 3, CA, CB)                            \
      }                                                                        \
      ENDBAR0;                                                                 \
    }
#pragma unroll 1
    for (int J = 0; J < NJ; ++J) {
      int i0 = 4 * J;
      C_BODY(0, paA, pbA, paB, pbB) C_BODY(1, paB, pbB, paA, pbA)
      C_BODY(2, paA, pbA, paB, pbB) C_BODY(3, paB, pbB, paA, pbA)
    }
#undef C_BODY
#undef C_STEP

  } else {
    // ===== wS: store-only (0 MFMA), items t = 4j-41+U, j in [10,138] =====
    float2 aoA[4], aoB[4];
#pragma unroll
    for (int s = 0; s < 4; ++s) { aoA[s] = make_float2(0.f, 0.f); aoB[s] = make_float2(0.f, 0.f); }

#define S_STEP(PB, U, CUR)                                                     \
    {                                                                          \
      int t = 4 * i - 41 + (U);                                                \
      if (t >= 0 && t < TSEQ && q == 0)                                        \
        o2[(size_t)t * NBAT + b0 + c] = CUR[U];                                \
    }
#define S_BODY(PB, CUR, NXT)                                                   \
    {                                                                          \
      int i = i0 + (PB);                                                       \
      NXT[0] = sAO[SRAO(PB, 0)][c];      /* top pre-reads (for i+1) */         \
      NXT[1] = sAO[SRAO(PB, 1)][c];                                            \
      NXT[2] = sAO[SRAO(PB, 2)][c];                                            \
      NXT[3] = sAO[SRAO(PB, 3)][c];                                            \
      SBAR;                                                                    \
      if (i >= 10 && i <= 138) {                                               \
        S_STEP(PB, 0, CUR) S_STEP(PB, 1, CUR)                                  \
        S_STEP(PB, 2, CUR) S_STEP(PB, 3, CUR)                                  \
      }                                                                        \
      ENDBAR0;                                                                 \
    }
#pragma unroll 1
    for (int J = 0; J < NJ; ++J) {
      int i0 = 4 * J;
      S_BODY(0, aoA, aoB) S_BODY(1, aoB, aoA)
      S_BODY(2, aoA, aoB) S_BODY(3, aoB, aoA)
    }
#undef S_BODY
#undef S_STEP
  }
}

extern "C" void kernel_launch(void* const* d_in, const int* in_sizes, int n_in,
                              void* d_out, int out_size, void* d_ws, size_t ws_size,
                              hipStream_t stream) {
  const float* x    = (const float*)d_in[0];
  const float* wih0 = (const float*)d_in[1];
  const float* whh0 = (const float*)d_in[2];
  const float* bih0 = (const float*)d_in[3];
  const float* bhh0 = (const float*)d_in[4];
  const float* wih1 = (const float*)d_in[5];
  const float* whh1 = (const float*)d_in[6];
  const float* bih1 = (const float*)d_in[7];
  const float* bhh1 = (const float*)d_in[8];
  const float* wih2 = (const float*)d_in[9];
  const float* whh2 = (const float*)d_in[10];
  const float* bih2 = (const float*)d_in[11];
  const float* bhh2 = (const float*)d_in[12];
  const float* wout = (const float*)d_in[13];
  const float* bout = (const float*)d_in[14];
  float* out = (float*)d_out;

  rnn3_p8r15<<<dim3(NBAT / 16), dim3(512), 0, stream>>>(
      x, wih0, whh0, bih0, bhh0, wih1, whh1, bih1, bhh1,
      wih2, whh2, bih2, bhh2, wout, bout, out);
}

// Round 16
// 72.957 us; speedup vs baseline: 1.1638x; 1.0035x over previous
//
#include <hip/hip_runtime.h>
#include <hip/hip_fp16.h>

// Fused 3-layer ReLU-RNN + linear head, MI355X (gfx950).
// T=512, B=4096, IN=4, H1=24, H2=48, H3=24, OUT=2.
//
// ROUND 16: round-15 kernel with ONE change — wB's per-step MFMA issue
// order retimed to cover the chained-C latencies on the critical cycle
// (fc -> b2 -> s2v -> pack fc):
//    b2, b0, b1, s2v, s0v, s1v
// b0/b1 (independent) sit between b2 and its C-consumer s2v; s0v/s1v sit
// between s2v and the fc pack. Dataflow bit-identical to rounds 14/15.
// All other waves and the interval/barrier skeleton unchanged.

#define TSEQ 512
#define NBAT 4096

typedef float    f32x4 __attribute__((ext_vector_type(4)));
typedef _Float16 f16x8 __attribute__((ext_vector_type(8)));
typedef _Float16 f16x2 __attribute__((ext_vector_type(2)));

union BFrag { f16x8 h; unsigned u[4]; };

__device__ __forceinline__ f32x4 MF(f16x8 a, f16x8 b, f32x4 c) {
  return __builtin_amdgcn_mfma_f32_16x16x32_f16(a, b, c, 0, 0, 0);
}
__device__ __forceinline__ unsigned pkh(float a, float b) {
  union { __half2 h2; unsigned u; } x;
  x.h2 = __floats2half2_rn(a, b);
  return x.u;
}
#if __has_builtin(__builtin_elementwise_max)
// relu applied in f16 after RN pack: relu(rn(x)) == rn(relu(x)) (mod +-0).
__device__ __forceinline__ unsigned pkr(float a, float b) {
  union { __half2 h2; f16x2 f; unsigned u; } x;
  x.h2 = __floats2half2_rn(a, b);
  f16x2 z = {(_Float16)0.f, (_Float16)0.f};
  x.f = __builtin_elementwise_max(x.f, z);
  return x.u;
}
#else
__device__ __forceinline__ unsigned pkr(float a, float b) {
  return pkh(fmaxf(a, 0.f), fmaxf(b, 0.f));
}
#endif

#define SBAR __builtin_amdgcn_sched_barrier(0)
// wait lgkmcnt(n) only (vmcnt=63, expcnt=7)
#define LGKM_WAIT(n) __builtin_amdgcn_s_waitcnt(0xC07F | ((n) << 8))
#define ENDBAR0                                                                \
  do {                                                                         \
    SBAR;                                                                      \
    LGKM_WAIT(0);                                                              \
    __builtin_amdgcn_s_barrier();                                              \
    SBAR;                                                                      \
  } while (0)

// ring-16 slot helpers (compile-time for constant PB,U; i0 = 4J so 4*i0 = 0 mod 16)
#define SW16(PB, U)  ((4 * (PB) + (U)) & 15)
#define SR16(PB, U)  ((4 * (PB) + (U) + 12) & 15)
// wC head-item slot (item tau-1 at step tau = 4i-32+U): (4PB+U+15)&15
#define SWAO(PB, U)  ((4 * (PB) + (U) + 15) & 15)
// wS pre-read slot (at interval j for items 4j-37+U): (4PB+U+11)&15
#define SRAO(PB, U)  ((4 * (PB) + (U) + 11) & 15)

struct WP { const float *wih0,*whh0,*wih1,*whh1,*wih2,*whh2,*wout; };

// Concatenated zero-padded weight views:
//  L0 (K=32): k<24 -> W_hh0[m][k], k in [28,32) -> W_ih0[m][k-28]
//  L1 (K=96): k<24 -> W_ih1[m][k], k in [32,80) -> W_hh1[m][k-32]
//  L2 (K=96): k<48 -> W_ih2[m][k], k in [64,88) -> W_hh2[m][k-64]
//  L3 (K=32): k<24 -> W_out[m][k], m<2
__device__ float wcat(int layer, int m, int k, const WP& P) {
  if (layer == 0) {
    if (m < 24) {
      if (k < 24) return P.whh0[m * 24 + k];
      if (k >= 28 && k < 32) return P.wih0[m * 4 + (k - 28)];
    }
    return 0.f;
  } else if (layer == 1) {
    if (m < 48) {
      if (k < 24) return P.wih1[m * 24 + k];
      if (k >= 32 && k < 80) return P.whh1[m * 48 + (k - 32)];
    }
    return 0.f;
  } else if (layer == 2) {
    if (m < 24) {
      if (k < 48) return P.wih2[m * 48 + k];
      if (k >= 64 && k < 88) return P.whh2[m * 24 + (k - 64)];
    }
    return 0.f;
  } else {
    if (m < 2 && k < 24) return P.wout[m * 24 + k];
    return 0.f;
  }
}

__device__ f16x8 afrag(int layer, int mt, int kc, const WP& P) {
  int m  = mt * 16 + (threadIdx.x & 15);
  int kb = kc * 32 + 4 * ((threadIdx.x >> 4) & 3);
  f16x8 r;
#pragma unroll
  for (int j = 0; j < 4; ++j) r[j] = (_Float16)wcat(layer, m, kb + j, P);
#pragma unroll
  for (int j = 0; j < 4; ++j) r[4 + j] = (_Float16)wcat(layer, m, kb + 16 + j, P);
  return r;
}

__device__ f32x4 cfrag(const float* b1, const float* b2, int mt, int nvalid) {
  int qq = (threadIdx.x >> 4) & 3;
  f32x4 r;
#pragma unroll
  for (int i = 0; i < 4; ++i) {
    int m = mt * 16 + 4 * qq + i;
    float v = 0.f;
    if (m < nvalid) { v = b1[m]; if (b2) v += b2[m]; }
    r[i] = v;
  }
  return r;
}

__global__ void __launch_bounds__(512)
rnn3_p8r16(const float* __restrict__ x,
           const float* __restrict__ wih0, const float* __restrict__ whh0,
           const float* __restrict__ bih0, const float* __restrict__ bhh0,
           const float* __restrict__ wih1, const float* __restrict__ whh1,
           const float* __restrict__ bih1, const float* __restrict__ bhh1,
           const float* __restrict__ wih2, const float* __restrict__ whh2,
           const float* __restrict__ bih2, const float* __restrict__ bhh2,
           const float* __restrict__ wout, const float* __restrict__ bout,
           float* __restrict__ out) {
  __shared__ uint4  sH1[16][64];      // h1 packs               16 KB
  __shared__ f32x4  sP1[16][3][64];   // partial1 f32           48 KB
  __shared__ uint4  sH2a[16][64];     // h2[0:32] packs         16 KB
  __shared__ uint2  sH2b[16][64];     // h2[32:48] packs         8 KB
  __shared__ f32x4  sP2a[16][64];     // partial2 mt0 f32       16 KB
  __shared__ f32x4  sP2b[16][64];     // partial2 mt1 f32       16 KB
  __shared__ float2 sAO[16][16];      // head outputs            2 KB

  const int tid  = threadIdx.x;
  const int wid  = tid >> 6;
  const int lane = tid & 63;
  const int c = lane & 15;
  const int q = lane >> 4;
  const int b0 = blockIdx.x * 16;

  WP P{wih0, whh0, wih1, whh1, wih2, whh2, wout};
  const float4* x4 = (const float4*)x;
  float2*       o2 = (float2*)out;

  const int NJ = 35;  // 140 intervals, i = 0..139

  if (wid == 0) {
    // ===== wA: h1 recurrence (2 MFMA/step), items t = 4i+U, i in [0,127] =====
    f16x8 A00 = afrag(0, 0, 0, P), A01 = afrag(0, 1, 0, P);
    f32x4 C00 = cfrag(bih0, bhh0, 0, 24), C01 = cfrag(bih0, bhh0, 1, 24);
    float4 xb[16];
#pragma unroll
    for (int s = 0; s < 16; ++s) xb[s] = x4[(size_t)s * NBAT + b0 + c];
    unsigned fa0 = 0u, fa1 = 0u, fa2 = 0u, fa3 = 0u;  // pure h1 packs

#define A_STEP(PB, U)                                                          \
    {                                                                          \
      float4 xs = xb[SW16(PB, U)];                                             \
      BFrag FAu;                                                               \
      FAu.u[0] = fa0; FAu.u[1] = fa1;                                          \
      FAu.u[2] = (q == 3) ? pkh(xs.x, xs.y) : fa2;                             \
      FAu.u[3] = (q == 3) ? pkh(xs.z, xs.w) : fa3;                             \
      f32x4 a10 = MF(A00, FAu.h, C00);                                         \
      f32x4 a11 = MF(A01, FAu.h, C01);                                         \
      {                                                                        \
        int t = 4 * i + (U);                                                   \
        int tn = (t + 16 < TSEQ) ? t + 16 : TSEQ - 1;                          \
        xb[SW16(PB, U)] = x4[(size_t)tn * NBAT + b0 + c];                      \
      }                                                                        \
      fa0 = pkr(a10[0], a10[1]); fa1 = pkr(a10[2], a10[3]);                    \
      fa2 = pkr(a11[0], a11[1]); fa3 = pkr(a11[2], a11[3]);                    \
      sH1[SW16(PB, U)][lane] = make_uint4(fa0, fa1, fa2, fa3);                 \
    }
#define A_BODY(PB)                                                             \
    {                                                                          \
      int i = i0 + (PB);                                                       \
      if (i <= 127) { A_STEP(PB, 0) A_STEP(PB, 1) A_STEP(PB, 2) A_STEP(PB, 3) }\
      ENDBAR0;                                                                 \
    }
#pragma unroll 1
    for (int J = 0; J < NJ; ++J) {
      int i0 = 4 * J;
      A_BODY(0) A_BODY(1) A_BODY(2) A_BODY(3)
    }
#undef A_BODY
#undef A_STEP

  } else if (wid == 1 || wid == 2) {
    // == wD (mt0,mt1) / wH (mt2): partial1(tau), tau = 4i-8+U, i in [2,129] ==
    const bool isD = (wid == 1);
    f16x8 W0 = afrag(1, isD ? 0 : 2, 0, P);
    f16x8 W1 = isD ? afrag(1, 1, 0, P) : W0;
    f32x4 Cb0 = cfrag(bih1, bhh1, isD ? 0 : 2, 48);
    f32x4 Cb1 = isD ? cfrag(bih1, bhh1, 1, 48) : Cb0;
    uint4 bufA[4], bufB[4];
#pragma unroll
    for (int s = 0; s < 4; ++s) { bufA[s] = make_uint4(0u,0u,0u,0u); bufB[s] = make_uint4(0u,0u,0u,0u); }

#define D_STEP(PB, U, CUR)                                                     \
    {                                                                          \
      BFrag FAu;                                                               \
      FAu.u[0] = CUR[U].x; FAu.u[1] = CUR[U].y;                                \
      FAu.u[2] = CUR[U].z; FAu.u[3] = CUR[U].w;                                \
      f32x4 p0 = MF(W0, FAu.h, Cb0);                                           \
      if (isD) {                                                               \
        f32x4 p1 = MF(W1, FAu.h, Cb1);                                         \
        sP1[SW16(PB, U)][0][lane] = p0;                                        \
        sP1[SW16(PB, U)][1][lane] = p1;                                        \
      } else {                                                                 \
        sP1[SW16(PB, U)][2][lane] = p0;                                        \
      }                                                                        \
    }
#define D_BODY(PB, CUR, NXT)                                                   \
    {                                                                          \
      int i = i0 + (PB);                                                       \
      NXT[0] = sH1[SR16(PB, 0)][lane];   /* top pre-reads (for i+1) */         \
      NXT[1] = sH1[SR16(PB, 1)][lane];                                         \
      NXT[2] = sH1[SR16(PB, 2)][lane];                                         \
      NXT[3] = sH1[SR16(PB, 3)][lane];                                         \
      SBAR;                                                                    \
      if (i >= 2 && i <= 129) {                                                \
        D_STEP(PB, 0, CUR) D_STEP(PB, 1, CUR)                                  \
        D_STEP(PB, 2, CUR) D_STEP(PB, 3, CUR)                                  \
      }                                                                        \
      ENDBAR0;                                                                 \
    }
#pragma unroll 1
    for (int J = 0; J < NJ; ++J) {
      int i0 = 4 * J;
      D_BODY(0, bufA, bufB) D_BODY(1, bufB, bufA)
      D_BODY(2, bufA, bufB) D_BODY(3, bufB, bufA)
    }
#undef D_BODY
#undef D_STEP

  } else if (wid == 3) {
    // ===== wB: h2 recurrence, items t = 4i-16+U, i in [4,131] =====
    // CHAINED-C with latency-covered issue order:
    //   b2, b0, b1, s2v, s0v, s1v ; pack fc first, then fb.
    f16x8 A1c1[3], A1c2[3];
#pragma unroll
    for (int mt = 0; mt < 3; ++mt) {
      A1c1[mt] = afrag(1, mt, 1, P);
      A1c2[mt] = afrag(1, mt, 2, P);
    }
    unsigned fb0 = 0u, fb1 = 0u, fb2 = 0u, fb3 = 0u, fc0 = 0u, fc1 = 0u;
    const f32x4 Z4 = {0.f, 0.f, 0.f, 0.f};
    f32x4 pA[4][3], pB[4][3];
#pragma unroll
    for (int s = 0; s < 4; ++s)
#pragma unroll
      for (int m = 0; m < 3; ++m) { pA[s][m] = Z4; pB[s][m] = Z4; }

#define B_STEPC(PB, U, CUR, H2A, H2B)                                          \
    {                                                                          \
      BFrag Ff, Gf;                                                            \
      Ff.u[0] = fb0; Ff.u[1] = fb1; Ff.u[2] = fb2; Ff.u[3] = fb3;              \
      Gf.u[0] = fc0; Gf.u[1] = fc1; Gf.u[2] = 0u; Gf.u[3] = 0u;                \
      f32x4 b2 = MF(A1c2[2], Gf.h, CUR[U][2]);   /* fc-chain head */           \
      f32x4 b0 = MF(A1c2[0], Gf.h, CUR[U][0]);   /* covers b2 latency */       \
      f32x4 b1 = MF(A1c2[1], Gf.h, CUR[U][1]);                                 \
      f32x4 s2v = MF(A1c1[2], Ff.h, b2);         /* C-chained */               \
      f32x4 s0v = MF(A1c1[0], Ff.h, b0);         /* covers s2v latency */      \
      f32x4 s1v = MF(A1c1[1], Ff.h, b1);                                       \
      fc0 = pkr(s2v[0], s2v[1]); fc1 = pkr(s2v[2], s2v[3]);                    \
      fb0 = pkr(s0v[0], s0v[1]); fb1 = pkr(s0v[2], s0v[3]);                    \
      fb2 = pkr(s1v[0], s1v[1]); fb3 = pkr(s1v[2], s1v[3]);                    \
      H2A[U] = make_uint4(fb0, fb1, fb2, fb3);                                 \
      H2B[U] = make_uint2(fc0, fc1);                                           \
    }
#define B_BODY(PB, CUR, NXT)                                                   \
    {                                                                          \
      int i = i0 + (PB);                                                       \
      NXT[0][0] = sP1[SR16(PB, 0)][0][lane];  /* top pre-reads (for i+1) */    \
      NXT[0][1] = sP1[SR16(PB, 0)][1][lane];                                   \
      NXT[0][2] = sP1[SR16(PB, 0)][2][lane];                                   \
      NXT[1][0] = sP1[SR16(PB, 1)][0][lane];                                   \
      NXT[1][1] = sP1[SR16(PB, 1)][1][lane];                                   \
      NXT[1][2] = sP1[SR16(PB, 1)][2][lane];                                   \
      NXT[2][0] = sP1[SR16(PB, 2)][0][lane];                                   \
      NXT[2][1] = sP1[SR16(PB, 2)][1][lane];                                   \
      NXT[2][2] = sP1[SR16(PB, 2)][2][lane];                                   \
      NXT[3][0] = sP1[SR16(PB, 3)][0][lane];                                   \
      NXT[3][1] = sP1[SR16(PB, 3)][1][lane];                                   \
      NXT[3][2] = sP1[SR16(PB, 3)][2][lane];                                   \
      SBAR;                                                                    \
      uint4 h2aq[4]; uint2 h2bq[4];                                            \
      if (i >= 4 && i <= 131) {                                                \
        B_STEPC(PB, 0, CUR, h2aq, h2bq)                                        \
        B_STEPC(PB, 1, CUR, h2aq, h2bq)                                        \
        B_STEPC(PB, 2, CUR, h2aq, h2bq)                                        \
        B_STEPC(PB, 3, CUR, h2aq, h2bq)                                        \
        sH2a[SW16(PB, 0)][lane] = h2aq[0];                                     \
        sH2b[SW16(PB, 0)][lane] = h2bq[0];                                     \
        sH2a[SW16(PB, 1)][lane] = h2aq[1];                                     \
        sH2b[SW16(PB, 1)][lane] = h2bq[1];                                     \
        sH2a[SW16(PB, 2)][lane] = h2aq[2];                                     \
        sH2b[SW16(PB, 2)][lane] = h2bq[2];                                     \
        sH2a[SW16(PB, 3)][lane] = h2aq[3];                                     \
        sH2b[SW16(PB, 3)][lane] = h2bq[3];                                     \
      }                                                                        \
      ENDBAR0;                                                                 \
    }
#pragma unroll 1
    for (int J = 0; J < NJ; ++J) {
      int i0 = 4 * J;
      B_BODY(0, pA, pB) B_BODY(1, pB, pA) B_BODY(2, pA, pB) B_BODY(3, pB, pA)
    }
#undef B_BODY
#undef B_STEPC

  } else if (wid == 4 || wid == 5) {
    // == wE (mt0) / wF (mt1): partial2(tau), tau = 4i-24+U, i in [6,133] ==
    const int mt = (wid == 4) ? 0 : 1;
    f16x8 W0 = afrag(2, mt, 0, P), W1 = afrag(2, mt, 1, P);
    f32x4 Cb = cfrag(bih2, bhh2, mt, 24);
    uint4 haA[4], haB[4];
    uint2 hbA[4], hbB[4];
#pragma unroll
    for (int s = 0; s < 4; ++s) {
      haA[s] = make_uint4(0u,0u,0u,0u); haB[s] = make_uint4(0u,0u,0u,0u);
      hbA[s] = make_uint2(0u,0u);       hbB[s] = make_uint2(0u,0u);
    }

#define E_STEP(PB, U, CA, CB)                                                  \
    {                                                                          \
      BFrag FBu, FCu;                                                          \
      FBu.u[0] = CA[U].x; FBu.u[1] = CA[U].y;                                  \
      FBu.u[2] = CA[U].z; FBu.u[3] = CA[U].w;                                  \
      FCu.u[0] = CB[U].x; FCu.u[1] = CB[U].y;                                  \
      FCu.u[2] = 0u; FCu.u[3] = 0u;                                            \
      f32x4 p = MF(W0, FBu.h, Cb);                                             \
      p = MF(W1, FCu.h, p);                                                    \
      if (mt == 0) sP2a[SW16(PB, U)][lane] = p;                                \
      else         sP2b[SW16(PB, U)][lane] = p;                                \
    }
#define E_BODY(PB, CA, CB, NA, NB)                                             \
    {                                                                          \
      int i = i0 + (PB);                                                       \
      NA[0] = sH2a[SR16(PB, 0)][lane];   /* top pre-reads (for i+1) */         \
      NA[1] = sH2a[SR16(PB, 1)][lane];                                         \
      NA[2] = sH2a[SR16(PB, 2)][lane];                                         \
      NA[3] = sH2a[SR16(PB, 3)][lane];                                         \
      NB[0] = sH2b[SR16(PB, 0)][lane];                                         \
      NB[1] = sH2b[SR16(PB, 1)][lane];                                         \
      NB[2] = sH2b[SR16(PB, 2)][lane];                                         \
      NB[3] = sH2b[SR16(PB, 3)][lane];                                         \
      SBAR;                                                                    \
      if (i >= 6 && i <= 133) {                                                \
        E_STEP(PB, 0, CA, CB) E_STEP(PB, 1, CA, CB)                            \
        E_STEP(PB, 2, CA, CB) E_STEP(PB, 3, CA, CB)                            \
      }                                                                        \
      ENDBAR0;                                                                 \
    }
#pragma unroll 1
    for (int J = 0; J < NJ; ++J) {
      int i0 = 4 * J;
      E_BODY(0, haA, hbA, haB, hbB) E_BODY(1, haB, hbB, haA, hbA)
      E_BODY(2, haA, hbA, haB, hbB) E_BODY(3, haB, hbB, haA, hbA)
    }
#undef E_BODY
#undef E_STEP

  } else if (wid == 6) {
    // ===== wC: h3 recurrence + head, steps tau = 4i-32+U, i in [8,136] =====
    f16x8 A2c2m0 = afrag(2, 0, 2, P), A2c2m1 = afrag(2, 1, 2, P);
    f16x8 A3 = afrag(3, 0, 0, P);
    f32x4 C3 = cfrag(bout, nullptr, 0, 2);
    unsigned fd0 = 0u, fd1 = 0u, fd2 = 0u, fd3 = 0u;
    const f32x4 Z4 = {0.f, 0.f, 0.f, 0.f};
    f32x4 paA[4], paB[4], pbA[4], pbB[4];
#pragma unroll
    for (int s = 0; s < 4; ++s) { paA[s] = Z4; paB[s] = Z4; pbA[s] = Z4; pbB[s] = Z4; }

#define C_STEP(PB, U, CA, CB)                                                  \
    {                                                                          \
      BFrag FDu;                                                               \
      FDu.u[0] = fd0; FDu.u[1] = fd1; FDu.u[2] = fd2; FDu.u[3] = fd3;          \
      f32x4 a30 = MF(A2c2m0, FDu.h, CA[U]);                                    \
      f32x4 a31 = MF(A2c2m1, FDu.h, CB[U]);                                    \
      f32x4 ao = MF(A3, FDu.h, C3);          /* head(tau-1) */                 \
      int th = 4 * i - 33 + (U);                                               \
      if (th >= 0 && th < TSEQ && q == 0)                                      \
        sAO[SWAO(PB, U)][c] = make_float2(ao[0], ao[1]);                       \
      fd0 = pkr(a30[0], a30[1]); fd1 = pkr(a30[2], a30[3]);                    \
      fd2 = pkr(a31[0], a31[1]); fd3 = pkr(a31[2], a31[3]);                    \
    }
#define C_BODY(PB, CA, CB, NA, NB)                                             \
    {                                                                          \
      int i = i0 + (PB);                                                       \
      NA[0] = sP2a[SR16(PB, 0)][lane];   /* top pre-reads (for i+1) */         \
      NA[1] = sP2a[SR16(PB, 1)][lane];                                         \
      NA[2] = sP2a[SR16(PB, 2)][lane];                                         \
      NA[3] = sP2a[SR16(PB, 3)][lane];                                         \
      NB[0] = sP2b[SR16(PB, 0)][lane];                                         \
      NB[1] = sP2b[SR16(PB, 1)][lane];                                         \
      NB[2] = sP2b[SR16(PB, 2)][lane];                                         \
      NB[3] = sP2b[SR16(PB, 3)][lane];                                         \
      SBAR;                                                                    \
      if (i >= 8 && i <= 136) {                                                \
        C_STEP(PB, 0, CA, CB) C_STEP(PB, 1, CA, CB)                            \
        C_STEP(PB, 2, CA, CB) C_STEP(PB, 3, CA, CB)                            \
      }                                                                        \
      ENDBAR0;                                                                 \
    }
#pragma unroll 1
    for (int J = 0; J < NJ; ++J) {
      int i0 = 4 * J;
      C_BODY(0, paA, pbA, paB, pbB) C_BODY(1, paB, pbB, paA, pbA)
      C_BODY(2, paA, pbA, paB, pbB) C_BODY(3, paB, pbB, paA, pbA)
    }
#undef C_BODY
#undef C_STEP

  } else {
    // ===== wS: store-only (0 MFMA), items t = 4j-41+U, j in [10,138] =====
    float2 aoA[4], aoB[4];
#pragma unroll
    for (int s = 0; s < 4; ++s) { aoA[s] = make_float2(0.f, 0.f); aoB[s] = make_float2(0.f, 0.f); }

#define S_STEP(PB, U, CUR)                                                     \
    {                                                                          \
      int t = 4 * i - 41 + (U);                                                \
      if (t >= 0 && t < TSEQ && q == 0)                                        \
        o2[(size_t)t * NBAT + b0 + c] = CUR[U];                                \
    }
#define S_BODY(PB, CUR, NXT)                                                   \
    {                                                                          \
      int i = i0 + (PB);                                                       \
      NXT[0] = sAO[SRAO(PB, 0)][c];      /* top pre-reads (for i+1) */         \
      NXT[1] = sAO[SRAO(PB, 1)][c];                                            \
      NXT[2] = sAO[SRAO(PB, 2)][c];                                            \
      NXT[3] = sAO[SRAO(PB, 3)][c];                                            \
      SBAR;                                                                    \
      if (i >= 10 && i <= 138) {                                               \
        S_STEP(PB, 0, CUR) S_STEP(PB, 1, CUR)                                  \
        S_STEP(PB, 2, CUR) S_STEP(PB, 3, CUR)                                  \
      }                                                                        \
      ENDBAR0;                                                                 \
    }
#pragma unroll 1
    for (int J = 0; J < NJ; ++J) {
      int i0 = 4 * J;
      S_BODY(0, aoA, aoB) S_BODY(1, aoB, aoA)
      S_BODY(2, aoA, aoB) S_BODY(3, aoB, aoA)
    }
#undef S_BODY
#undef S_STEP
  }
}

extern "C" void kernel_launch(void* const* d_in, const int* in_sizes, int n_in,
                              void* d_out, int out_size, void* d_ws, size_t ws_size,
                              hipStream_t stream) {
  const float* x    = (const float*)d_in[0];
  const float* wih0 = (const float*)d_in[1];
  const float* whh0 = (const float*)d_in[2];
  const float* bih0 = (const float*)d_in[3];
  const float* bhh0 = (const float*)d_in[4];
  const float* wih1 = (const float*)d_in[5];
  const float* whh1 = (const float*)d_in[6];
  const float* bih1 = (const float*)d_in[7];
  const float* bhh1 = (const float*)d_in[8];
  const float* wih2 = (const float*)d_in[9];
  const float* whh2 = (const float*)d_in[10];
  const float* bih2 = (const float*)d_in[11];
  const float* bhh2 = (const float*)d_in[12];
  const float* wout = (const float*)d_in[13];
  const float* bout = (const float*)d_in[14];
  float* out = (float*)d_out;

  rnn3_p8r16<<<dim3(NBAT / 16), dim3(512), 0, stream>>>(
      x, wih0, whh0, bih0, bhh0, wih1, whh1, bih1, bhh1,
      wih2, whh2, bih2, bhh2, wout, bout, out);
}